// Round 1
// baseline (371.127 us; speedup 1.0000x reference)
//
#include <hip/hip_runtime.h>
#include <math.h>

#define LL 1024
#define DD 768
#define HH 12
#define CL 32
#define NC 32   // LL / CL
#define NBH 24  // B*H

__device__ __forceinline__ float wave_sum64(float v) {
#pragma unroll
  for (int off = 32; off; off >>= 1) v += __shfl_xor(v, off, 64);
  return v;
}

__device__ __forceinline__ float sigm(float x) { return 1.0f / (1.0f + expf(-x)); }

// ---------------- K1: causal depthwise conv (k=3) + residual + LayerNorm ----
__global__ __launch_bounds__(256) void conv_ln_kernel(
    const float* __restrict__ x, const float* __restrict__ cw,
    const float* __restrict__ cb, const float* __restrict__ g,
    const float* __restrict__ bta, float* __restrict__ xn) {
  int row = blockIdx.x;            // b*L + l
  int l = row & (LL - 1);
  const float* xr = x + (size_t)row * DD;
  __shared__ float red[16];
  float vals[3];
  float s = 0.f, ss = 0.f;
#pragma unroll
  for (int i = 0; i < 3; i++) {
    int d = threadIdx.x + i * 256;
    float x0 = xr[d];
    float xm1 = (l >= 1) ? xr[d - DD] : 0.f;
    float xm2 = (l >= 2) ? xr[d - 2 * DD] : 0.f;
    float c = xm2 * cw[d * 3 + 0] + xm1 * cw[d * 3 + 1] + x0 * cw[d * 3 + 2] + cb[d];
    float v = x0 + c;
    vals[i] = v; s += v; ss += v * v;
  }
  s = wave_sum64(s); ss = wave_sum64(ss);
  int wid = threadIdx.x >> 6;
  if ((threadIdx.x & 63) == 0) { red[wid * 2] = s; red[wid * 2 + 1] = ss; }
  __syncthreads();
  if (threadIdx.x == 0) {
    red[8] = red[0] + red[2] + red[4] + red[6];
    red[9] = red[1] + red[3] + red[5] + red[7];
  }
  __syncthreads();
  float mu = red[8] * (1.f / 768.f);
  float var = red[9] * (1.f / 768.f) - mu * mu;
  float inv = rsqrtf(var + 1e-5f);
  float* xo = xn + (size_t)row * DD;
#pragma unroll
  for (int i = 0; i < 3; i++) {
    int d = threadIdx.x + i * 256;
    xo[d] = (vals[i] - mu) * inv * g[d] + bta[d];
  }
}

// ---------------- K2: generic fp32 GEMM  C = A(M,K) * B(N,K)^T + bias -------
// MODE 0: none; MODE 1: qkv epilogue (elu+1 on n<1536); MODE 2: silu
template <int MODE, bool HASBIAS>
__global__ __launch_bounds__(256) void gemm_nt_kernel(
    const float* __restrict__ A, const float* __restrict__ Bm,
    const float* __restrict__ bias, float* __restrict__ C,
    int M, int N, int K) {
  __shared__ float As[16][68];   // [k][m], padded stride 68 (16B-aligned rows)
  __shared__ float Bs[16][68];   // [k][n]
  int m0 = blockIdx.y * 64, n0 = blockIdx.x * 64;
  int tid = threadIdx.x;
  int lrow = tid >> 2;           // 0..63
  int lcol = (tid & 3) << 2;     // 0,4,8,12
  const float* Ap = A + (size_t)(m0 + lrow) * K + lcol;
  const float* Bp = Bm + (size_t)(n0 + lrow) * K + lcol;
  int ty = tid >> 4, tx = tid & 15;
  float acc[4][4] = {{0.f}};
  for (int k0 = 0; k0 < K; k0 += 16) {
    float4 av = *(const float4*)(Ap + k0);
    float4 bv = *(const float4*)(Bp + k0);
    __syncthreads();
    As[lcol + 0][lrow] = av.x; As[lcol + 1][lrow] = av.y;
    As[lcol + 2][lrow] = av.z; As[lcol + 3][lrow] = av.w;
    Bs[lcol + 0][lrow] = bv.x; Bs[lcol + 1][lrow] = bv.y;
    Bs[lcol + 2][lrow] = bv.z; Bs[lcol + 3][lrow] = bv.w;
    __syncthreads();
#pragma unroll
    for (int kk = 0; kk < 16; kk++) {
      float4 a4 = *(const float4*)&As[kk][ty << 2];
      float4 b4 = *(const float4*)&Bs[kk][tx << 2];
      float ar[4] = {a4.x, a4.y, a4.z, a4.w};
      float br[4] = {b4.x, b4.y, b4.z, b4.w};
#pragma unroll
      for (int i = 0; i < 4; i++)
#pragma unroll
        for (int j = 0; j < 4; j++) acc[i][j] = fmaf(ar[i], br[j], acc[i][j]);
    }
  }
#pragma unroll
  for (int i = 0; i < 4; i++) {
    int m = m0 + (ty << 2) + i;
    float tmp[4];
#pragma unroll
    for (int j = 0; j < 4; j++) {
      int n = n0 + (tx << 2) + j;
      float v = acc[i][j];
      if (HASBIAS) v += bias[n];
      if (MODE == 1) { if (n < 1536) v = (v > 0.f) ? v + 1.f : expf(v); }
      if (MODE == 2) { v = v / (1.f + expf(-v)); }
      tmp[j] = v;
    }
    float4 o; o.x = tmp[0]; o.y = tmp[1]; o.z = tmp[2]; o.w = tmp[3];
    *(float4*)&C[(size_t)m * N + n0 + (tx << 2)] = o;
  }
}

// ---------------- K3: bn2 (60x256) + param transforms -> gate, decay --------
__global__ __launch_bounds__(64) void params_kernel(
    const float* __restrict__ hbuf, const float* __restrict__ w2,
    const float* __restrict__ temp, float* __restrict__ gate,
    float* __restrict__ dec) {
  int row = blockIdx.x;            // b*L + l
  __shared__ float hs[256];
  __shared__ float ps[64];
  int tid = threadIdx.x;
  ((float4*)hs)[tid] = ((const float4*)(hbuf + (size_t)row * 256))[tid];
  __syncthreads();
  if (tid < 60) {
    const float* w = w2 + tid * 256;
    float s = 0.f;
#pragma unroll 8
    for (int k = 0; k < 256; k++) s = fmaf(hs[k], w[k], s);
    ps[tid] = s;
  }
  __syncthreads();
  if (tid < HH) {
    float p0 = ps[tid * 5 + 0], p1 = ps[tid * 5 + 1], p2 = ps[tid * 5 + 2],
          p3 = ps[tid * 5 + 3], p4 = ps[tid * 5 + 4];
    const float PI = 3.14159265358979323846f;
    float sa = sigm(p0);
    float sp = tanhf(p1) * PI;
    float ca = sigm(p2);
    float cp = tanhf(p3) * PI;
    float dc = 0.3f + 0.65f * sigm(p4);
    float gt = sigm(sa * ca * cosf(sp - cp) * temp[0]);
    gate[row * HH + tid] = gt;               // (B,L,H) -> second output
    int b = row >> 10, l = row & 1023;
    dec[((b * HH + tid) << 10) + l] = dc;    // (B,H,L) for the scan
  }
}

// ---------------- K4: df = exp(cumsum(log decay)) per (b,h) -----------------
__global__ __launch_bounds__(64) void df_kernel(const float* __restrict__ dec,
                                                float* __restrict__ df) {
  int bh = blockIdx.x;
  int lane = threadIdx.x;
  const float* dp = dec + (size_t)bh * LL + lane * 16;
  double ls[16];
  double s = 0.0;
#pragma unroll
  for (int i = 0; i < 16; i++) { s += (double)logf(dp[i]); ls[i] = s; }
  double tot = s;
  double run = tot;
#pragma unroll
  for (int off = 1; off < 64; off <<= 1) {
    double n = __shfl_up(run, off, 64);
    if (lane >= off) run += n;
  }
  double excl = run - tot;
  float* dfo = df + (size_t)bh * LL + lane * 16;
#pragma unroll
  for (int i = 0; i < 16; i++) dfo[i] = expf((float)(excl + ls[i]));
}

// ---------------- K5: scan phase1 — per-chunk local end state ---------------
// lane e owns column KV[:,e] (64 regs). KV[t] = a_t*KV[t-1] + clip(k d x v e *c)*r
__global__ __launch_bounds__(64) void scan_phase1(
    const float* __restrict__ qkv, const float* __restrict__ dec,
    const float* __restrict__ df, const float* __restrict__ gate,
    float* __restrict__ kvcs, float* __restrict__ zcs, float* __restrict__ Aarr) {
  int blk = blockIdx.x;            // bh*NC + c
  int bh = blk >> 5, c = blk & (NC - 1);
  int b = bh / HH, h = bh - b * HH;
  int e = threadIdx.x;
  int t0 = c * CL;
  __shared__ float kbuf[CL][64];
  __shared__ float vbuf[CL][64];
  __shared__ float sbuf[CL][4];
  const float* kb = qkv + ((size_t)(b * LL + t0)) * 2304 + 768 + h * 64;
  for (int t = 0; t < CL; t++) {
    kbuf[t][e] = kb[(size_t)t * 2304 + e];
    vbuf[t][e] = kb[(size_t)t * 2304 + 768 + e];
  }
  if (e < CL) {
    int t = t0 + e;
    float a = dec[bh * LL + t];
    float d = df[bh * LL + t];
    float r = d / (d + 1e-8f);
    float g = gate[(b * LL + t) * HH + h];
    sbuf[e][0] = a; sbuf[e][1] = r; sbuf[e][2] = g * (1.f - a);
  }
  __syncthreads();
  float KV[64];
#pragma unroll
  for (int d = 0; d < 64; d++) KV[d] = 0.f;
  float z = 0.f, A = 1.f;
  for (int t = 0; t < CL; t++) {
    float a = sbuf[t][0], r = sbuf[t][1], cs = sbuf[t][2];
    float ke = kbuf[t][e];
    float vc = vbuf[t][e] * cs;
    A *= a;
#pragma unroll
    for (int d4 = 0; d4 < 16; d4++) {
      float4 k4 = *(const float4*)&kbuf[t][d4 << 2];
      float kr[4] = {k4.x, k4.y, k4.z, k4.w};
#pragma unroll
      for (int j = 0; j < 4; j++) {
        float u = fminf(fmaxf(kr[j] * vc, -5.f), 5.f);
        KV[(d4 << 2) + j] = fmaf(a, KV[(d4 << 2) + j], r * u);
      }
    }
    z = fmaf(a, z, ke * (1.f - a) * r);
  }
  float* kvo = kvcs + (size_t)blk * 4096 + e;
#pragma unroll
  for (int d = 0; d < 64; d++) kvo[d * 64] = KV[d];
  zcs[blk * 64 + e] = z;
  if (e == 0) Aarr[blk] = A;
}

// ---------------- K6: sequential carry combine (in-place end->init) ---------
__global__ __launch_bounds__(256) void combine_kernel(
    const float* __restrict__ Aarr, float* __restrict__ kv, float* __restrict__ z) {
  int g = blockIdx.x * 256 + threadIdx.x;
  if (g < NBH * 4096) {
    int bh = g >> 12, idx = g & 4095;
    const float* Ap = Aarr + bh * NC;
    float* p = kv + (size_t)bh * NC * 4096 + idx;
    float carry = 0.f;
#pragma unroll
    for (int c = 0; c < NC; c++) {
      float endv = p[(size_t)c * 4096];
      p[(size_t)c * 4096] = carry;          // init state for chunk c
      carry = fmaf(Ap[c], carry, endv);     // state entering chunk c+1
    }
  } else {
    int g2 = g - NBH * 4096;
    int bh = g2 >> 6, idx = g2 & 63;
    const float* Ap = Aarr + bh * NC;
    float* p = z + bh * NC * 64 + idx;
    float carry = 0.f;
#pragma unroll
    for (int c = 0; c < NC; c++) {
      float endv = p[c * 64];
      p[c * 64] = carry;
      carry = fmaf(Ap[c], carry, endv);
    }
  }
}

// ---------------- K7: scan phase3 — replay + out_num/den + head LN ----------
__global__ __launch_bounds__(64) void scan_phase3(
    const float* __restrict__ qkv, const float* __restrict__ dec,
    const float* __restrict__ df, const float* __restrict__ gate,
    const float* __restrict__ kvcs, const float* __restrict__ zcs,
    const float* __restrict__ mng, const float* __restrict__ mnb,
    float* __restrict__ att) {
  int blk = blockIdx.x;
  int bh = blk >> 5, c = blk & (NC - 1);
  int b = bh / HH, h = bh - b * HH;
  int e = threadIdx.x;
  int t0 = c * CL;
  __shared__ float kbuf[CL][64];
  __shared__ float vbuf[CL][64];
  __shared__ float qbuf[CL][64];
  __shared__ float sbuf[CL][4];
  const float* qb = qkv + ((size_t)(b * LL + t0)) * 2304 + h * 64;
  for (int t = 0; t < CL; t++) {
    qbuf[t][e] = qb[(size_t)t * 2304 + e];
    kbuf[t][e] = qb[(size_t)t * 2304 + 768 + e];
    vbuf[t][e] = qb[(size_t)t * 2304 + 1536 + e];
  }
  if (e < CL) {
    int t = t0 + e;
    float a = dec[bh * LL + t];
    float d = df[bh * LL + t];
    float r = d / (d + 1e-8f);
    float g = gate[(b * LL + t) * HH + h];
    sbuf[e][0] = a; sbuf[e][1] = r; sbuf[e][2] = g * (1.f - a);
  }
  float KV[64];
  const float* kvi = kvcs + (size_t)blk * 4096 + e;
#pragma unroll
  for (int d = 0; d < 64; d++) KV[d] = kvi[d * 64];
  float z = zcs[blk * 64 + e];
  float mg = mng[e], mb = mnb[e];
  __syncthreads();
  for (int t = 0; t < CL; t++) {
    float a = sbuf[t][0], r = sbuf[t][1], cs = sbuf[t][2];
    float ke = kbuf[t][e];
    float qe = qbuf[t][e];
    float vc = vbuf[t][e] * cs;
    float on = 0.f;
#pragma unroll
    for (int d4 = 0; d4 < 16; d4++) {
      float4 k4 = *(const float4*)&kbuf[t][d4 << 2];
      float4 q4 = *(const float4*)&qbuf[t][d4 << 2];
      float kr[4] = {k4.x, k4.y, k4.z, k4.w};
      float qr[4] = {q4.x, q4.y, q4.z, q4.w};
#pragma unroll
      for (int j = 0; j < 4; j++) {
        float u = fminf(fmaxf(kr[j] * vc, -5.f), 5.f);
        float nv = fmaf(a, KV[(d4 << 2) + j], r * u);
        KV[(d4 << 2) + j] = nv;
        on = fmaf(qr[j], nv, on);
      }
    }
    z = fmaf(a, z, ke * (1.f - a) * r);
    float zc = fminf(fmaxf(z, -10000.f), 10000.f);
    float den = wave_sum64(qe * zc) + 1e-4f;
    float o = on / den;
    float mu = wave_sum64(o) * (1.f / 64.f);
    float dl = o - mu;
    float var = wave_sum64(dl * dl) * (1.f / 64.f);
    float outv = dl * rsqrtf(var + 1e-5f) * mg + mb;
    att[((size_t)(b * LL + t0 + t)) * DD + h * 64 + e] = outv;
  }
}

// ---------------------------------------------------------------------------
extern "C" void kernel_launch(void* const* d_in, const int* in_sizes, int n_in,
                              void* d_out, int out_size, void* d_ws, size_t ws_size,
                              hipStream_t stream) {
  (void)in_sizes; (void)n_in; (void)out_size; (void)ws_size;
  const float* x           = (const float*)d_in[0];
  const float* conv_w      = (const float*)d_in[1];
  const float* conv_b      = (const float*)d_in[2];
  const float* ln_g        = (const float*)d_in[3];
  const float* ln_b        = (const float*)d_in[4];
  const float* qkv_w       = (const float*)d_in[5];
  const float* qkv_b       = (const float*)d_in[6];
  const float* bn_w1       = (const float*)d_in[7];
  const float* bn_w2       = (const float*)d_in[8];
  const float* temperature = (const float*)d_in[9];
  const float* proj_w      = (const float*)d_in[10];
  const float* proj_b      = (const float*)d_in[11];
  const float* mn_g        = (const float*)d_in[12];
  const float* mn_b        = (const float*)d_in[13];

  float* y    = (float*)d_out;
  float* gate = y + 2 * 1024 * 768;      // outputs concatenated: y then gate

  char* ws = (char*)d_ws;
  float* xn   = (float*)(ws);                  // 6.29 MB ; reused as att after bn1
  float* att  = xn;
  float* qkva = (float*)(ws + 6291456);        // 18.87 MB (q_f | k_f | v per row)
  float* hbuf = (float*)(ws + 25165824);       // 2.10 MB
  float* dec  = (float*)(ws + 27262976);       // 96 KB  (B,H,L)
  float* dfb  = (float*)(ws + 27361280);       // 96 KB
  float* kvcs = (float*)(ws + 27459584);       // 12.58 MB (chunk end -> init, in place)
  float* zcs  = (float*)(ws + 40042496);       // 192 KB
  float* Aarr = (float*)(ws + 40239104);       // 3 KB

  conv_ln_kernel<<<2048, 256, 0, stream>>>(x, conv_w, conv_b, ln_g, ln_b, xn);

  // qkv = xn @ qkv_w.T + b, with elu+1 on q,k in the epilogue
  gemm_nt_kernel<1, true><<<dim3(36, 32), 256, 0, stream>>>(
      xn, qkv_w, qkv_b, qkva, 2048, 2304, 768);

  // h = silu(xn @ bn_w1.T)   (no bias)
  gemm_nt_kernel<2, false><<<dim3(4, 32), 256, 0, stream>>>(
      xn, bn_w1, nullptr, hbuf, 2048, 256, 768);

  params_kernel<<<2048, 64, 0, stream>>>(hbuf, bn_w2, temperature, gate, dec);

  df_kernel<<<NBH, 64, 0, stream>>>(dec, dfb);

  scan_phase1<<<NBH * NC, 64, 0, stream>>>(qkva, dec, dfb, gate, kvcs, zcs, Aarr);

  combine_kernel<<<390, 256, 0, stream>>>(Aarr, kvcs, zcs);

  scan_phase3<<<NBH * NC, 64, 0, stream>>>(qkva, dec, dfb, gate, kvcs, zcs,
                                           mn_g, mn_b, att);

  // y = att @ proj_w.T + proj_b
  gemm_nt_kernel<0, true><<<dim3(12, 32), 256, 0, stream>>>(
      att, proj_w, proj_b, y, 2048, 768, 768);
}

// Round 2
// 244.960 us; speedup vs baseline: 1.5151x; 1.5151x over previous
//
#include <hip/hip_runtime.h>
#include <math.h>

#define LL 1024
#define DD 768
#define HH 12
#define CL 32
#define NC 32   // LL / CL
#define NBH 24  // B*H

typedef __bf16 bf16x8 __attribute__((ext_vector_type(8)));
typedef __bf16 bf16x4 __attribute__((ext_vector_type(4)));
typedef float floatx4 __attribute__((ext_vector_type(4)));

typedef const void __attribute__((address_space(1)))* gas_ptr;
typedef void __attribute__((address_space(3)))* las_ptr;

__device__ __forceinline__ void gl_lds16(const void* g, void* s) {
  __builtin_amdgcn_global_load_lds((gas_ptr)g, (las_ptr)s, 16, 0, 0);
}

__device__ __forceinline__ float wave_sum64(float v) {
#pragma unroll
  for (int off = 32; off; off >>= 1) v += __shfl_xor(v, off, 64);
  return v;
}

__device__ __forceinline__ float sigm(float x) { return 1.0f / (1.0f + expf(-x)); }

// ---------------- K0: fp32 -> bf16 convert (weights) ------------------------
__global__ __launch_bounds__(256) void f2bf_kernel(const float* __restrict__ s,
                                                   __bf16* __restrict__ d, int n4) {
  int i = blockIdx.x * 256 + threadIdx.x;
  if (i < n4) {
    float4 v = ((const float4*)s)[i];
    bf16x4 o;
    o[0] = (__bf16)v.x; o[1] = (__bf16)v.y; o[2] = (__bf16)v.z; o[3] = (__bf16)v.w;
    ((bf16x4*)d)[i] = o;
  }
}

// ---------------- K1: causal depthwise conv (k=3) + residual + LN -> bf16 ---
__global__ __launch_bounds__(256) void conv_ln_kernel(
    const float* __restrict__ x, const float* __restrict__ cw,
    const float* __restrict__ cb, const float* __restrict__ g,
    const float* __restrict__ bta, __bf16* __restrict__ xn) {
  int row = blockIdx.x;            // b*L + l
  int l = row & (LL - 1);
  const float* xr = x + (size_t)row * DD;
  __shared__ float red[16];
  float vals[3];
  float s = 0.f, ss = 0.f;
#pragma unroll
  for (int i = 0; i < 3; i++) {
    int d = threadIdx.x + i * 256;
    float x0 = xr[d];
    float xm1 = (l >= 1) ? xr[d - DD] : 0.f;
    float xm2 = (l >= 2) ? xr[d - 2 * DD] : 0.f;
    float c = xm2 * cw[d * 3 + 0] + xm1 * cw[d * 3 + 1] + x0 * cw[d * 3 + 2] + cb[d];
    float v = x0 + c;
    vals[i] = v; s += v; ss += v * v;
  }
  s = wave_sum64(s); ss = wave_sum64(ss);
  int wid = threadIdx.x >> 6;
  if ((threadIdx.x & 63) == 0) { red[wid * 2] = s; red[wid * 2 + 1] = ss; }
  __syncthreads();
  if (threadIdx.x == 0) {
    red[8] = red[0] + red[2] + red[4] + red[6];
    red[9] = red[1] + red[3] + red[5] + red[7];
  }
  __syncthreads();
  float mu = red[8] * (1.f / 768.f);
  float var = red[9] * (1.f / 768.f) - mu * mu;
  float inv = rsqrtf(var + 1e-5f);
  __bf16* xo = xn + (size_t)row * DD;
#pragma unroll
  for (int i = 0; i < 3; i++) {
    int d = threadIdx.x + i * 256;
    xo[d] = (__bf16)((vals[i] - mu) * inv * g[d] + bta[d]);
  }
}

// ---------------- K2: bf16 MFMA GEMM  C = A(M,K) * B(N,K)^T + bias ----------
// 128x128 tile, BK=64, global_load_lds staging, XOR-swizzled LDS (2-way free).
// MODE 0: none; MODE 1: qkv epilogue (elu+1 on n<1536); MODE 2: silu
template <int MODE, bool HASBIAS>
__global__ __launch_bounds__(256) void gemm_mfma_kernel(
    const __bf16* __restrict__ A, const __bf16* __restrict__ Bw,
    const float* __restrict__ bias, float* __restrict__ C,
    int M, int N, int K) {
  __shared__ __attribute__((aligned(16))) __bf16 As[128 * 64];
  __shared__ __attribute__((aligned(16))) __bf16 Bs[128 * 64];
  int m0 = blockIdx.y * 128, n0 = blockIdx.x * 128;
  int tid = threadIdx.x;
  int w = tid >> 6, lane = tid & 63;
  int wm = w >> 1, wn = w & 1;          // wave grid 2x2, each wave 64x64
  int quad = lane >> 4, l16 = lane & 15;

  // staging: per round r (4 rounds for A, 4 for B), wave w covers 8 rows.
  int lrow = lane >> 3;                  // 0..7 row within wave-call
  int lchunk = (lane & 7) ^ lrow;        // swizzled source chunk (slot s holds c=s^row&7)
  int R0 = w * 8;

  floatx4 acc[4][4];
#pragma unroll
  for (int i = 0; i < 4; i++)
#pragma unroll
    for (int j = 0; j < 4; j++) acc[i][j] = (floatx4)0.f;

  for (int k0 = 0; k0 < K; k0 += 64) {
    __syncthreads();   // previous iter's LDS reads done before overwrite
#pragma unroll
    for (int r = 0; r < 4; r++) {
      int row = r * 32 + R0 + lrow;
      gl_lds16(A + (size_t)(m0 + row) * K + k0 + lchunk * 8, &As[(r * 32 + R0) * 64]);
      gl_lds16(Bw + (size_t)(n0 + row) * K + k0 + lchunk * 8, &Bs[(r * 32 + R0) * 64]);
    }
    __syncthreads();   // drains vmcnt then barrier
#pragma unroll
    for (int s = 0; s < 2; s++) {
      bf16x8 af[4], bfr[4];
      int csw = (s << 2) + quad;
#pragma unroll
      for (int i = 0; i < 4; i++) {
        int m = wm * 64 + i * 16 + l16;
        af[i] = *(const bf16x8*)&As[m * 64 + (csw ^ (l16 & 7)) * 8];
      }
#pragma unroll
      for (int j = 0; j < 4; j++) {
        int n = wn * 64 + j * 16 + l16;
        bfr[j] = *(const bf16x8*)&Bs[n * 64 + (csw ^ (l16 & 7)) * 8];
      }
#pragma unroll
      for (int i = 0; i < 4; i++)
#pragma unroll
        for (int j = 0; j < 4; j++)
          acc[i][j] = __builtin_amdgcn_mfma_f32_16x16x32_bf16(af[i], bfr[j], acc[i][j], 0, 0, 0);
    }
  }
  // epilogue: D[row=quad*4+r][col=l16] per 16x16 tile
#pragma unroll
  for (int j = 0; j < 4; j++) {
    int gcol = n0 + wn * 64 + j * 16 + l16;
    float bv = HASBIAS ? bias[gcol] : 0.f;
#pragma unroll
    for (int i = 0; i < 4; i++) {
      int grow = m0 + wm * 64 + i * 16 + quad * 4;
#pragma unroll
      for (int r = 0; r < 4; r++) {
        float v = acc[i][j][r] + bv;
        if (MODE == 1) { if (gcol < 1536) v = (v > 0.f) ? v + 1.f : expf(v); }
        if (MODE == 2) { v = v / (1.f + expf(-v)); }
        C[(size_t)(grow + r) * N + gcol] = v;
      }
    }
  }
}

// ---------------- K3: bn2 (60x256) + param transforms -> gate, decay --------
__global__ __launch_bounds__(64) void params_kernel(
    const float* __restrict__ hbuf, const float* __restrict__ w2,
    const float* __restrict__ temp, float* __restrict__ gate,
    float* __restrict__ dec) {
  int row = blockIdx.x;            // b*L + l
  __shared__ float hs[256];
  __shared__ float ps[64];
  int tid = threadIdx.x;
  ((float4*)hs)[tid] = ((const float4*)(hbuf + (size_t)row * 256))[tid];
  __syncthreads();
  if (tid < 60) {
    const float* w = w2 + tid * 256;
    float s = 0.f;
#pragma unroll 8
    for (int k = 0; k < 256; k++) s = fmaf(hs[k], w[k], s);
    ps[tid] = s;
  }
  __syncthreads();
  if (tid < HH) {
    float p0 = ps[tid * 5 + 0], p1 = ps[tid * 5 + 1], p2 = ps[tid * 5 + 2],
          p3 = ps[tid * 5 + 3], p4 = ps[tid * 5 + 4];
    const float PI = 3.14159265358979323846f;
    float sa = sigm(p0);
    float sp = tanhf(p1) * PI;
    float ca = sigm(p2);
    float cp = tanhf(p3) * PI;
    float dc = 0.3f + 0.65f * sigm(p4);
    float gt = sigm(sa * ca * cosf(sp - cp) * temp[0]);
    gate[row * HH + tid] = gt;               // (B,L,H) -> second output
    int b = row >> 10, l = row & 1023;
    dec[((b * HH + tid) << 10) + l] = dc;    // (B,H,L) for the scan
  }
}

// ---------------- K4: df = exp(cumsum(log decay)) per (b,h) -----------------
__global__ __launch_bounds__(64) void df_kernel(const float* __restrict__ dec,
                                                float* __restrict__ df) {
  int bh = blockIdx.x;
  int lane = threadIdx.x;
  const float* dp = dec + (size_t)bh * LL + lane * 16;
  double ls[16];
  double s = 0.0;
#pragma unroll
  for (int i = 0; i < 16; i++) { s += (double)logf(dp[i]); ls[i] = s; }
  double tot = s;
  double run = tot;
#pragma unroll
  for (int off = 1; off < 64; off <<= 1) {
    double n = __shfl_up(run, off, 64);
    if (lane >= off) run += n;
  }
  double excl = run - tot;
  float* dfo = df + (size_t)bh * LL + lane * 16;
#pragma unroll
  for (int i = 0; i < 16; i++) dfo[i] = expf((float)(excl + ls[i]));
}

// ---------------- K5: scan phase1 — per-chunk local end state ---------------
__global__ __launch_bounds__(64) void scan_phase1(
    const float* __restrict__ qkv, const float* __restrict__ dec,
    const float* __restrict__ df, const float* __restrict__ gate,
    float* __restrict__ kvcs, float* __restrict__ zcs, float* __restrict__ Aarr) {
  int blk = blockIdx.x;            // bh*NC + c
  int bh = blk >> 5, c = blk & (NC - 1);
  int b = bh / HH, h = bh - b * HH;
  int e = threadIdx.x;
  int t0 = c * CL;
  __shared__ float kbuf[CL][64];
  __shared__ float vbuf[CL][64];
  __shared__ float sbuf[CL][4];
  const float* kb = qkv + ((size_t)(b * LL + t0)) * 2304 + 768 + h * 64;
  for (int t = 0; t < CL; t++) {
    kbuf[t][e] = kb[(size_t)t * 2304 + e];
    vbuf[t][e] = kb[(size_t)t * 2304 + 768 + e];
  }
  if (e < CL) {
    int t = t0 + e;
    float a = dec[bh * LL + t];
    float d = df[bh * LL + t];
    float r = d / (d + 1e-8f);
    float g = gate[(b * LL + t) * HH + h];
    sbuf[e][0] = a; sbuf[e][1] = r; sbuf[e][2] = g * (1.f - a);
  }
  __syncthreads();
  float KV[64];
#pragma unroll
  for (int d = 0; d < 64; d++) KV[d] = 0.f;
  float z = 0.f, A = 1.f;
  for (int t = 0; t < CL; t++) {
    float a = sbuf[t][0], r = sbuf[t][1], cs = sbuf[t][2];
    float ke = kbuf[t][e];
    float vc = vbuf[t][e] * cs;
    A *= a;
#pragma unroll
    for (int d4 = 0; d4 < 16; d4++) {
      float4 k4 = *(const float4*)&kbuf[t][d4 << 2];
      float kr[4] = {k4.x, k4.y, k4.z, k4.w};
#pragma unroll
      for (int j = 0; j < 4; j++) {
        float u = fminf(fmaxf(kr[j] * vc, -5.f), 5.f);
        KV[(d4 << 2) + j] = fmaf(a, KV[(d4 << 2) + j], r * u);
      }
    }
    z = fmaf(a, z, ke * (1.f - a) * r);
  }
  float* kvo = kvcs + (size_t)blk * 4096 + e;
#pragma unroll
  for (int d = 0; d < 64; d++) kvo[d * 64] = KV[d];
  zcs[blk * 64 + e] = z;
  if (e == 0) Aarr[blk] = A;
}

// ---------------- K6: sequential carry combine (in-place end->init) ---------
__global__ __launch_bounds__(256) void combine_kernel(
    const float* __restrict__ Aarr, float* __restrict__ kv, float* __restrict__ z) {
  int g = blockIdx.x * 256 + threadIdx.x;
  if (g < NBH * 4096) {
    int bh = g >> 12, idx = g & 4095;
    const float* Ap = Aarr + bh * NC;
    float* p = kv + (size_t)bh * NC * 4096 + idx;
    float carry = 0.f;
#pragma unroll
    for (int c = 0; c < NC; c++) {
      float endv = p[(size_t)c * 4096];
      p[(size_t)c * 4096] = carry;          // init state for chunk c
      carry = fmaf(Ap[c], carry, endv);     // state entering chunk c+1
    }
  } else {
    int g2 = g - NBH * 4096;
    int bh = g2 >> 6, idx = g2 & 63;
    const float* Ap = Aarr + bh * NC;
    float* p = z + bh * NC * 64 + idx;
    float carry = 0.f;
#pragma unroll
    for (int c = 0; c < NC; c++) {
      float endv = p[c * 64];
      p[c * 64] = carry;
      carry = fmaf(Ap[c], carry, endv);
    }
  }
}

// ---------------- K7: scan phase3 — replay + out_num/den + head LN -> bf16 --
__global__ __launch_bounds__(64) void scan_phase3(
    const float* __restrict__ qkv, const float* __restrict__ dec,
    const float* __restrict__ df, const float* __restrict__ gate,
    const float* __restrict__ kvcs, const float* __restrict__ zcs,
    const float* __restrict__ mng, const float* __restrict__ mnb,
    __bf16* __restrict__ att) {
  int blk = blockIdx.x;
  int bh = blk >> 5, c = blk & (NC - 1);
  int b = bh / HH, h = bh - b * HH;
  int e = threadIdx.x;
  int t0 = c * CL;
  __shared__ float kbuf[CL][64];
  __shared__ float vbuf[CL][64];
  __shared__ float qbuf[CL][64];
  __shared__ float sbuf[CL][4];
  const float* qb = qkv + ((size_t)(b * LL + t0)) * 2304 + h * 64;
  for (int t = 0; t < CL; t++) {
    qbuf[t][e] = qb[(size_t)t * 2304 + e];
    kbuf[t][e] = qb[(size_t)t * 2304 + 768 + e];
    vbuf[t][e] = qb[(size_t)t * 2304 + 1536 + e];
  }
  if (e < CL) {
    int t = t0 + e;
    float a = dec[bh * LL + t];
    float d = df[bh * LL + t];
    float r = d / (d + 1e-8f);
    float g = gate[(b * LL + t) * HH + h];
    sbuf[e][0] = a; sbuf[e][1] = r; sbuf[e][2] = g * (1.f - a);
  }
  float KV[64];
  const float* kvi = kvcs + (size_t)blk * 4096 + e;
#pragma unroll
  for (int d = 0; d < 64; d++) KV[d] = kvi[d * 64];
  float z = zcs[blk * 64 + e];
  float mg = mng[e], mb = mnb[e];
  __syncthreads();
  for (int t = 0; t < CL; t++) {
    float a = sbuf[t][0], r = sbuf[t][1], cs = sbuf[t][2];
    float ke = kbuf[t][e];
    float qe = qbuf[t][e];
    float vc = vbuf[t][e] * cs;
    float on = 0.f;
#pragma unroll
    for (int d4 = 0; d4 < 16; d4++) {
      float4 k4 = *(const float4*)&kbuf[t][d4 << 2];
      float4 q4 = *(const float4*)&qbuf[t][d4 << 2];
      float kr[4] = {k4.x, k4.y, k4.z, k4.w};
      float qr[4] = {q4.x, q4.y, q4.z, q4.w};
#pragma unroll
      for (int j = 0; j < 4; j++) {
        float u = fminf(fmaxf(kr[j] * vc, -5.f), 5.f);
        float nv = fmaf(a, KV[(d4 << 2) + j], r * u);
        KV[(d4 << 2) + j] = nv;
        on = fmaf(qr[j], nv, on);
      }
    }
    z = fmaf(a, z, ke * (1.f - a) * r);
    float zc = fminf(fmaxf(z, -10000.f), 10000.f);
    float den = wave_sum64(qe * zc) + 1e-4f;
    float o = on / den;
    float mu = wave_sum64(o) * (1.f / 64.f);
    float dl = o - mu;
    float var = wave_sum64(dl * dl) * (1.f / 64.f);
    float outv = dl * rsqrtf(var + 1e-5f) * mg + mb;
    att[((size_t)(b * LL + t0 + t)) * DD + h * 64 + e] = (__bf16)outv;
  }
}

// ---------------------------------------------------------------------------
extern "C" void kernel_launch(void* const* d_in, const int* in_sizes, int n_in,
                              void* d_out, int out_size, void* d_ws, size_t ws_size,
                              hipStream_t stream) {
  (void)in_sizes; (void)n_in; (void)out_size; (void)ws_size;
  const float* x           = (const float*)d_in[0];
  const float* conv_w      = (const float*)d_in[1];
  const float* conv_b      = (const float*)d_in[2];
  const float* ln_g        = (const float*)d_in[3];
  const float* ln_b        = (const float*)d_in[4];
  const float* qkv_w       = (const float*)d_in[5];
  const float* qkv_b       = (const float*)d_in[6];
  const float* bn_w1       = (const float*)d_in[7];
  const float* bn_w2       = (const float*)d_in[8];
  const float* temperature = (const float*)d_in[9];
  const float* proj_w      = (const float*)d_in[10];
  const float* proj_b      = (const float*)d_in[11];
  const float* mn_g        = (const float*)d_in[12];
  const float* mn_b        = (const float*)d_in[13];

  float* y    = (float*)d_out;
  float* gate = y + 2 * 1024 * 768;      // outputs concatenated: y then gate

  char* ws = (char*)d_ws;
  __bf16* xn_bf  = (__bf16*)(ws);                 // 3.15 MB, reused as att_bf
  __bf16* att_bf = xn_bf;                         // alias (xn dead before phase3)
  float* qkva = (float*)(ws + 3145728);           // 18.87 MB (q_f | k_f | v per row)
  float* hbuf = (float*)(ws + 22020096);          // 2.10 MB
  float* dec  = (float*)(ws + 24117248);          // 96 KB  (B,H,L)
  float* dfb  = (float*)(ws + 24215552);          // 96 KB
  float* kvcs = (float*)(ws + 24313856);          // 12.58 MB (end->init in place)
  __bf16* qkvw_bf = (__bf16*)(ws + 24313856);     // 3.54 MB alias (dead before phase1)
  float* zcs  = (float*)(ws + 36896768);          // 192 KB
  float* Aarr = (float*)(ws + 37093376);          // 3 KB
  __bf16* bnw1_bf = (__bf16*)(ws + 37096448);     // 0.39 MB
  __bf16* projw_bf = (__bf16*)(ws + 37489664);    // 1.18 MB   -> total 38.7 MB

  // weight converts (fp32 -> bf16)
  f2bf_kernel<<<1728, 256, 0, stream>>>(qkv_w, qkvw_bf, 442368);
  f2bf_kernel<<<192, 256, 0, stream>>>(bn_w1, bnw1_bf, 49152);
  f2bf_kernel<<<576, 256, 0, stream>>>(proj_w, projw_bf, 147456);

  conv_ln_kernel<<<2048, 256, 0, stream>>>(x, conv_w, conv_b, ln_g, ln_b, xn_bf);

  // qkv = xn @ qkv_w.T + b, with elu+1 on q,k in the epilogue
  gemm_mfma_kernel<1, true><<<dim3(18, 16), 256, 0, stream>>>(
      xn_bf, qkvw_bf, qkv_b, qkva, 2048, 2304, 768);

  // h = silu(xn @ bn_w1.T)   (no bias)
  gemm_mfma_kernel<2, false><<<dim3(2, 16), 256, 0, stream>>>(
      xn_bf, bnw1_bf, nullptr, hbuf, 2048, 256, 768);

  params_kernel<<<2048, 64, 0, stream>>>(hbuf, bn_w2, temperature, gate, dec);

  df_kernel<<<NBH, 64, 0, stream>>>(dec, dfb);

  scan_phase1<<<NBH * NC, 64, 0, stream>>>(qkva, dec, dfb, gate, kvcs, zcs, Aarr);

  combine_kernel<<<390, 256, 0, stream>>>(Aarr, kvcs, zcs);

  scan_phase3<<<NBH * NC, 64, 0, stream>>>(qkva, dec, dfb, gate, kvcs, zcs,
                                           mn_g, mn_b, att_bf);

  // y = att @ proj_w.T + proj_b
  gemm_mfma_kernel<0, true><<<dim3(6, 16), 256, 0, stream>>>(
      att_bf, projw_bf, proj_b, y, 2048, 768, 768);
}

// Round 3
// 238.850 us; speedup vs baseline: 1.5538x; 1.0256x over previous
//
#include <hip/hip_runtime.h>
#include <math.h>

#define LL 1024
#define DD 768
#define HH 12
#define CL 16
#define NC 64   // LL / CL
#define NBH 24  // B*H

typedef __bf16 bf16x8 __attribute__((ext_vector_type(8)));
typedef __bf16 bf16x4 __attribute__((ext_vector_type(4)));
typedef float floatx4 __attribute__((ext_vector_type(4)));

typedef const void __attribute__((address_space(1)))* gas_ptr;
typedef void __attribute__((address_space(3)))* las_ptr;

__device__ __forceinline__ void gl_lds16(const void* g, void* s) {
  __builtin_amdgcn_global_load_lds((gas_ptr)g, (las_ptr)s, 16, 0, 0);
}

__device__ __forceinline__ float wave_sum64(float v) {
#pragma unroll
  for (int off = 32; off; off >>= 1) v += __shfl_xor(v, off, 64);
  return v;
}

__device__ __forceinline__ float sigm(float x) { return 1.0f / (1.0f + expf(-x)); }

// ---------------- K0: fp32 -> bf16 convert (weights) ------------------------
__global__ __launch_bounds__(256) void f2bf_kernel(const float* __restrict__ s,
                                                   __bf16* __restrict__ d, int n4) {
  int i = blockIdx.x * 256 + threadIdx.x;
  if (i < n4) {
    float4 v = ((const float4*)s)[i];
    bf16x4 o;
    o[0] = (__bf16)v.x; o[1] = (__bf16)v.y; o[2] = (__bf16)v.z; o[3] = (__bf16)v.w;
    ((bf16x4*)d)[i] = o;
  }
}

// ---------------- K1: causal depthwise conv (k=3) + residual + LN -> bf16 ---
__global__ __launch_bounds__(256) void conv_ln_kernel(
    const float* __restrict__ x, const float* __restrict__ cw,
    const float* __restrict__ cb, const float* __restrict__ g,
    const float* __restrict__ bta, __bf16* __restrict__ xn) {
  int row = blockIdx.x;            // b*L + l
  int l = row & (LL - 1);
  const float* xr = x + (size_t)row * DD;
  __shared__ float red[16];
  float vals[3];
  float s = 0.f, ss = 0.f;
#pragma unroll
  for (int i = 0; i < 3; i++) {
    int d = threadIdx.x + i * 256;
    float x0 = xr[d];
    float xm1 = (l >= 1) ? xr[d - DD] : 0.f;
    float xm2 = (l >= 2) ? xr[d - 2 * DD] : 0.f;
    float c = xm2 * cw[d * 3 + 0] + xm1 * cw[d * 3 + 1] + x0 * cw[d * 3 + 2] + cb[d];
    float v = x0 + c;
    vals[i] = v; s += v; ss += v * v;
  }
  s = wave_sum64(s); ss = wave_sum64(ss);
  int wid = threadIdx.x >> 6;
  if ((threadIdx.x & 63) == 0) { red[wid * 2] = s; red[wid * 2 + 1] = ss; }
  __syncthreads();
  if (threadIdx.x == 0) {
    red[8] = red[0] + red[2] + red[4] + red[6];
    red[9] = red[1] + red[3] + red[5] + red[7];
  }
  __syncthreads();
  float mu = red[8] * (1.f / 768.f);
  float var = red[9] * (1.f / 768.f) - mu * mu;
  float inv = rsqrtf(var + 1e-5f);
  __bf16* xo = xn + (size_t)row * DD;
#pragma unroll
  for (int i = 0; i < 3; i++) {
    int d = threadIdx.x + i * 256;
    xo[d] = (__bf16)((vals[i] - mu) * inv * g[d] + bta[d]);
  }
}

// ---------------- K2: bf16 MFMA GEMM  C = A(M,K) * B(N,K)^T + bias ----------
// MODE 0: none; MODE 1: qkv epilogue (elu+1 on n<1536); MODE 2: silu
template <int MODE, bool HASBIAS>
__global__ __launch_bounds__(256) void gemm_mfma_kernel(
    const __bf16* __restrict__ A, const __bf16* __restrict__ Bw,
    const float* __restrict__ bias, float* __restrict__ C,
    int M, int N, int K) {
  __shared__ __attribute__((aligned(16))) __bf16 As[128 * 64];
  __shared__ __attribute__((aligned(16))) __bf16 Bs[128 * 64];
  int m0 = blockIdx.y * 128, n0 = blockIdx.x * 128;
  int tid = threadIdx.x;
  int w = tid >> 6, lane = tid & 63;
  int wm = w >> 1, wn = w & 1;          // wave grid 2x2, each wave 64x64
  int quad = lane >> 4, l16 = lane & 15;

  int lrow = lane >> 3;                  // 0..7 row within wave-call
  int lchunk = (lane & 7) ^ lrow;        // swizzled source chunk
  int R0 = w * 8;

  floatx4 acc[4][4];
#pragma unroll
  for (int i = 0; i < 4; i++)
#pragma unroll
    for (int j = 0; j < 4; j++) acc[i][j] = (floatx4)0.f;

  for (int k0 = 0; k0 < K; k0 += 64) {
    __syncthreads();
#pragma unroll
    for (int r = 0; r < 4; r++) {
      int row = r * 32 + R0 + lrow;
      gl_lds16(A + (size_t)(m0 + row) * K + k0 + lchunk * 8, &As[(r * 32 + R0) * 64]);
      gl_lds16(Bw + (size_t)(n0 + row) * K + k0 + lchunk * 8, &Bs[(r * 32 + R0) * 64]);
    }
    __syncthreads();
#pragma unroll
    for (int s = 0; s < 2; s++) {
      bf16x8 af[4], bfr[4];
      int csw = (s << 2) + quad;
#pragma unroll
      for (int i = 0; i < 4; i++) {
        int m = wm * 64 + i * 16 + l16;
        af[i] = *(const bf16x8*)&As[m * 64 + (csw ^ (l16 & 7)) * 8];
      }
#pragma unroll
      for (int j = 0; j < 4; j++) {
        int n = wn * 64 + j * 16 + l16;
        bfr[j] = *(const bf16x8*)&Bs[n * 64 + (csw ^ (l16 & 7)) * 8];
      }
#pragma unroll
      for (int i = 0; i < 4; i++)
#pragma unroll
        for (int j = 0; j < 4; j++)
          acc[i][j] = __builtin_amdgcn_mfma_f32_16x16x32_bf16(af[i], bfr[j], acc[i][j], 0, 0, 0);
    }
  }
#pragma unroll
  for (int j = 0; j < 4; j++) {
    int gcol = n0 + wn * 64 + j * 16 + l16;
    float bv = HASBIAS ? bias[gcol] : 0.f;
#pragma unroll
    for (int i = 0; i < 4; i++) {
      int grow = m0 + wm * 64 + i * 16 + quad * 4;
#pragma unroll
      for (int r = 0; r < 4; r++) {
        float v = acc[i][j][r] + bv;
        if (MODE == 1) { if (gcol < 1536) v = (v > 0.f) ? v + 1.f : expf(v); }
        if (MODE == 2) { v = v / (1.f + expf(-v)); }
        C[(size_t)(grow + r) * N + gcol] = v;
      }
    }
  }
}

// ---------------- K3: bn2 (60x256) + param transforms -> gate, decay --------
__global__ __launch_bounds__(64) void params_kernel(
    const float* __restrict__ hbuf, const float* __restrict__ w2,
    const float* __restrict__ temp, float* __restrict__ gate,
    float* __restrict__ dec) {
  int row = blockIdx.x;            // b*L + l
  __shared__ float hs[256];
  __shared__ float ps[64];
  int tid = threadIdx.x;
  ((float4*)hs)[tid] = ((const float4*)(hbuf + (size_t)row * 256))[tid];
  __syncthreads();
  if (tid < 60) {
    const float* w = w2 + tid * 256;
    float s = 0.f;
#pragma unroll 8
    for (int k = 0; k < 256; k++) s = fmaf(hs[k], w[k], s);
    ps[tid] = s;
  }
  __syncthreads();
  if (tid < HH) {
    float p0 = ps[tid * 5 + 0], p1 = ps[tid * 5 + 1], p2 = ps[tid * 5 + 2],
          p3 = ps[tid * 5 + 3], p4 = ps[tid * 5 + 4];
    const float PI = 3.14159265358979323846f;
    float sa = sigm(p0);
    float sp = tanhf(p1) * PI;
    float ca = sigm(p2);
    float cp = tanhf(p3) * PI;
    float dc = 0.3f + 0.65f * sigm(p4);
    float gt = sigm(sa * ca * cosf(sp - cp) * temp[0]);
    gate[row * HH + tid] = gt;               // (B,L,H) -> second output
    int b = row >> 10, l = row & 1023;
    dec[((b * HH + tid) << 10) + l] = dc;    // (B,H,L) for the scan
  }
}

// ---------------- K4: df = exp(cumsum(log decay)) per (b,h) -----------------
__global__ __launch_bounds__(64) void df_kernel(const float* __restrict__ dec,
                                                float* __restrict__ df) {
  int bh = blockIdx.x;
  int lane = threadIdx.x;
  const float* dp = dec + (size_t)bh * LL + lane * 16;
  double ls[16];
  double s = 0.0;
#pragma unroll
  for (int i = 0; i < 16; i++) { s += (double)logf(dp[i]); ls[i] = s; }
  double tot = s;
  double run = tot;
#pragma unroll
  for (int off = 1; off < 64; off <<= 1) {
    double n = __shfl_up(run, off, 64);
    if (lane >= off) run += n;
  }
  double excl = run - tot;
  float* dfo = df + (size_t)bh * LL + lane * 16;
#pragma unroll
  for (int i = 0; i < 16; i++) dfo[i] = expf((float)(excl + ls[i]));
}

// ---------------- K5: scan phase1 — per-chunk local end state ---------------
__global__ __launch_bounds__(64) void scan_phase1(
    const float* __restrict__ qkv, const float* __restrict__ dec,
    const float* __restrict__ df, const float* __restrict__ gate,
    float* __restrict__ kvcs, float* __restrict__ zcs, float* __restrict__ Aarr) {
  int blk = blockIdx.x;            // bh*NC + c
  int bh = blk >> 6, c = blk & (NC - 1);
  int b = bh / HH, h = bh - b * HH;
  int e = threadIdx.x;
  int t0 = c * CL;
  __shared__ float kbuf[CL][64];
  __shared__ float vbuf[CL][64];
  __shared__ float sbuf[CL][4];
  const float* kb = qkv + ((size_t)(b * LL + t0)) * 2304 + 768 + h * 64;
  for (int t = 0; t < CL; t++) {
    kbuf[t][e] = kb[(size_t)t * 2304 + e];
    vbuf[t][e] = kb[(size_t)t * 2304 + 768 + e];
  }
  if (e < CL) {
    int t = t0 + e;
    float a = dec[bh * LL + t];
    float d = df[bh * LL + t];
    float r = d / (d + 1e-8f);
    float g = gate[(b * LL + t) * HH + h];
    sbuf[e][0] = a; sbuf[e][1] = r; sbuf[e][2] = g * (1.f - a);
  }
  __syncthreads();
  float KV[64];
#pragma unroll
  for (int d = 0; d < 64; d++) KV[d] = 0.f;
  float z = 0.f, A = 1.f;
  for (int t = 0; t < CL; t++) {
    float a = sbuf[t][0], r = sbuf[t][1], cs = sbuf[t][2];
    float ke = kbuf[t][e];
    float vc = vbuf[t][e] * cs;
    A *= a;
#pragma unroll
    for (int d4 = 0; d4 < 16; d4++) {
      float4 k4 = *(const float4*)&kbuf[t][d4 << 2];
      float kr[4] = {k4.x, k4.y, k4.z, k4.w};
#pragma unroll
      for (int j = 0; j < 4; j++) {
        float u = fminf(fmaxf(kr[j] * vc, -5.f), 5.f);
        KV[(d4 << 2) + j] = fmaf(a, KV[(d4 << 2) + j], r * u);
      }
    }
    z = fmaf(a, z, ke * (1.f - a) * r);
  }
  float* kvo = kvcs + (size_t)blk * 4096 + e;
#pragma unroll
  for (int d = 0; d < 64; d++) kvo[d * 64] = KV[d];
  zcs[blk * 64 + e] = z;
  if (e == 0) Aarr[blk] = A;
}

// ---------------- K6: sequential carry combine (in-place end->init) ---------
__global__ __launch_bounds__(256) void combine_kernel(
    const float* __restrict__ Aarr, float* __restrict__ kv, float* __restrict__ z) {
  int g = blockIdx.x * 256 + threadIdx.x;
  if (g < NBH * 4096) {
    int bh = g >> 12, idx = g & 4095;
    const float* Ap = Aarr + bh * NC;
    float* p = kv + (size_t)bh * NC * 4096 + idx;
    float carry = 0.f;
#pragma unroll 8
    for (int c = 0; c < NC; c++) {
      float endv = p[(size_t)c * 4096];
      p[(size_t)c * 4096] = carry;          // init state for chunk c
      carry = fmaf(Ap[c], carry, endv);     // state entering chunk c+1
    }
  } else {
    int g2 = g - NBH * 4096;
    int bh = g2 >> 6, idx = g2 & 63;
    const float* Ap = Aarr + bh * NC;
    float* p = z + bh * NC * 64 + idx;
    float carry = 0.f;
#pragma unroll 8
    for (int c = 0; c < NC; c++) {
      float endv = p[c * 64];
      p[c * 64] = carry;
      carry = fmaf(Ap[c], carry, endv);
    }
  }
}

// ---------------- K7: scan phase3 — replay + out_num/den + head LN -> bf16 --
__global__ __launch_bounds__(64) void scan_phase3(
    const float* __restrict__ qkv, const float* __restrict__ dec,
    const float* __restrict__ df, const float* __restrict__ gate,
    const float* __restrict__ kvcs, const float* __restrict__ zcs,
    const float* __restrict__ mng, const float* __restrict__ mnb,
    __bf16* __restrict__ att) {
  int blk = blockIdx.x;
  int bh = blk >> 6, c = blk & (NC - 1);
  int b = bh / HH, h = bh - b * HH;
  int e = threadIdx.x;
  int t0 = c * CL;
  __shared__ float kbuf[CL][64];
  __shared__ float vbuf[CL][64];
  __shared__ float qbuf[CL][64];
  __shared__ float sbuf[CL][4];
  const float* qb = qkv + ((size_t)(b * LL + t0)) * 2304 + h * 64;
  for (int t = 0; t < CL; t++) {
    qbuf[t][e] = qb[(size_t)t * 2304 + e];
    kbuf[t][e] = qb[(size_t)t * 2304 + 768 + e];
    vbuf[t][e] = qb[(size_t)t * 2304 + 1536 + e];
  }
  if (e < CL) {
    int t = t0 + e;
    float a = dec[bh * LL + t];
    float d = df[bh * LL + t];
    float r = d / (d + 1e-8f);
    float g = gate[(b * LL + t) * HH + h];
    sbuf[e][0] = a; sbuf[e][1] = r; sbuf[e][2] = g * (1.f - a);
  }
  float KV[64];
  const float* kvi = kvcs + (size_t)blk * 4096 + e;
#pragma unroll
  for (int d = 0; d < 64; d++) KV[d] = kvi[d * 64];
  float z = zcs[blk * 64 + e];
  float mg = mng[e], mb = mnb[e];
  __syncthreads();
  for (int t = 0; t < CL; t++) {
    float a = sbuf[t][0], r = sbuf[t][1], cs = sbuf[t][2];
    float ke = kbuf[t][e];
    float qe = qbuf[t][e];
    float vc = vbuf[t][e] * cs;
    float on = 0.f;
#pragma unroll
    for (int d4 = 0; d4 < 16; d4++) {
      float4 k4 = *(const float4*)&kbuf[t][d4 << 2];
      float4 q4 = *(const float4*)&qbuf[t][d4 << 2];
      float kr[4] = {k4.x, k4.y, k4.z, k4.w};
      float qr[4] = {q4.x, q4.y, q4.z, q4.w};
#pragma unroll
      for (int j = 0; j < 4; j++) {
        float u = fminf(fmaxf(kr[j] * vc, -5.f), 5.f);
        float nv = fmaf(a, KV[(d4 << 2) + j], r * u);
        KV[(d4 << 2) + j] = nv;
        on = fmaf(qr[j], nv, on);
      }
    }
    z = fmaf(a, z, ke * (1.f - a) * r);
    float zc = fminf(fmaxf(z, -10000.f), 10000.f);
    // single fused butterfly: den = sum(q*z), S1 = sum(on), S2 = sum(on^2)
    float s0 = qe * zc, s1 = on, s2 = on * on;
#pragma unroll
    for (int off = 32; off; off >>= 1) {
      s0 += __shfl_xor(s0, off, 64);
      s1 += __shfl_xor(s1, off, 64);
      s2 += __shfl_xor(s2, off, 64);
    }
    float den = s0 + 1e-4f;
    float idn = 1.f / den;
    float o = on * idn;
    float mu = s1 * idn * (1.f / 64.f);
    float E2 = s2 * idn * idn * (1.f / 64.f);
    float var = E2 - mu * mu;
    float outv = (o - mu) * rsqrtf(var + 1e-5f) * mg + mb;
    att[((size_t)(b * LL + t0 + t)) * DD + h * 64 + e] = (__bf16)outv;
  }
}

// ---------------------------------------------------------------------------
extern "C" void kernel_launch(void* const* d_in, const int* in_sizes, int n_in,
                              void* d_out, int out_size, void* d_ws, size_t ws_size,
                              hipStream_t stream) {
  (void)in_sizes; (void)n_in; (void)out_size; (void)ws_size;
  const float* x           = (const float*)d_in[0];
  const float* conv_w      = (const float*)d_in[1];
  const float* conv_b      = (const float*)d_in[2];
  const float* ln_g        = (const float*)d_in[3];
  const float* ln_b        = (const float*)d_in[4];
  const float* qkv_w       = (const float*)d_in[5];
  const float* qkv_b       = (const float*)d_in[6];
  const float* bn_w1       = (const float*)d_in[7];
  const float* bn_w2       = (const float*)d_in[8];
  const float* temperature = (const float*)d_in[9];
  const float* proj_w      = (const float*)d_in[10];
  const float* proj_b      = (const float*)d_in[11];
  const float* mn_g        = (const float*)d_in[12];
  const float* mn_b        = (const float*)d_in[13];

  float* y    = (float*)d_out;
  float* gate = y + 2 * 1024 * 768;      // outputs concatenated: y then gate

  char* ws = (char*)d_ws;
  __bf16* xn_bf  = (__bf16*)(ws);                 // 3.15 MB, reused as att_bf
  __bf16* att_bf = xn_bf;                         // alias (xn dead before phase3)
  float* qkva = (float*)(ws + 3145728);           // 18.87 MB (q_f | k_f | v per row)
  float* hbuf = (float*)(ws + 22020096);          // 2.10 MB
  float* dec  = (float*)(ws + 24117248);          // 96 KB  (B,H,L)
  float* dfb  = (float*)(ws + 24215552);          // 96 KB
  float* kvcs = (float*)(ws + 24313856);          // 25.17 MB (end->init in place)
  __bf16* qkvw_bf = (__bf16*)(ws + 24313856);     // 3.54 MB alias (dead before phase1)
  float* zcs  = (float*)(ws + 49479680);          // 384 KB
  float* Aarr = (float*)(ws + 49872896);          // 6 KB
  __bf16* bnw1_bf = (__bf16*)(ws + 49879040);     // 0.39 MB
  __bf16* projw_bf = (__bf16*)(ws + 50272256);    // 1.18 MB -> total 51.5 MB

  // weight converts (fp32 -> bf16)
  f2bf_kernel<<<1728, 256, 0, stream>>>(qkv_w, qkvw_bf, 442368);
  f2bf_kernel<<<192, 256, 0, stream>>>(bn_w1, bnw1_bf, 49152);
  f2bf_kernel<<<576, 256, 0, stream>>>(proj_w, projw_bf, 147456);

  conv_ln_kernel<<<2048, 256, 0, stream>>>(x, conv_w, conv_b, ln_g, ln_b, xn_bf);

  // qkv = xn @ qkv_w.T + b, with elu+1 on q,k in the epilogue
  gemm_mfma_kernel<1, true><<<dim3(18, 16), 256, 0, stream>>>(
      xn_bf, qkvw_bf, qkv_b, qkva, 2048, 2304, 768);

  // h = silu(xn @ bn_w1.T)   (no bias)
  gemm_mfma_kernel<2, false><<<dim3(2, 16), 256, 0, stream>>>(
      xn_bf, bnw1_bf, nullptr, hbuf, 2048, 256, 768);

  params_kernel<<<2048, 64, 0, stream>>>(hbuf, bn_w2, temperature, gate, dec);

  df_kernel<<<NBH, 64, 0, stream>>>(dec, dfb);

  scan_phase1<<<NBH * NC, 64, 0, stream>>>(qkva, dec, dfb, gate, kvcs, zcs, Aarr);

  combine_kernel<<<390, 256, 0, stream>>>(Aarr, kvcs, zcs);

  scan_phase3<<<NBH * NC, 64, 0, stream>>>(qkva, dec, dfb, gate, kvcs, zcs,
                                           mn_g, mn_b, att_bf);

  // y = att @ proj_w.T + proj_b
  gemm_mfma_kernel<0, true><<<dim3(6, 16), 256, 0, stream>>>(
      att_bf, projw_bf, proj_b, y, 2048, 768, 768);
}

// Round 4
// 220.046 us; speedup vs baseline: 1.6866x; 1.0855x over previous
//
#include <hip/hip_runtime.h>
#include <math.h>

#define LL 1024
#define DD 768
#define HH 12
#define CL 16
#define NC 64   // LL / CL
#define NBH 24  // B*H

typedef __bf16 bf16x8 __attribute__((ext_vector_type(8)));
typedef __bf16 bf16x4 __attribute__((ext_vector_type(4)));
typedef float floatx4 __attribute__((ext_vector_type(4)));

typedef const void __attribute__((address_space(1)))* gas_ptr;
typedef void __attribute__((address_space(3)))* las_ptr;

__device__ __forceinline__ void gl_lds16(const void* g, void* s) {
  __builtin_amdgcn_global_load_lds((gas_ptr)g, (las_ptr)s, 16, 0, 0);
}

__device__ __forceinline__ float wave_sum64(float v) {
#pragma unroll
  for (int off = 32; off; off >>= 1) v += __shfl_xor(v, off, 64);
  return v;
}

__device__ __forceinline__ float sigm(float x) { return 1.0f / (1.0f + expf(-x)); }

// ---------------- K0: fp32 -> bf16 convert (weights) ------------------------
__global__ __launch_bounds__(256) void f2bf_kernel(const float* __restrict__ s,
                                                   __bf16* __restrict__ d, int n4) {
  int i = blockIdx.x * 256 + threadIdx.x;
  if (i < n4) {
    float4 v = ((const float4*)s)[i];
    bf16x4 o;
    o[0] = (__bf16)v.x; o[1] = (__bf16)v.y; o[2] = (__bf16)v.z; o[3] = (__bf16)v.w;
    ((bf16x4*)d)[i] = o;
  }
}

// w2 (60x256 fp32) -> padded 128x256 bf16 (rows >= 60 zero)
__global__ __launch_bounds__(256) void w2pad_kernel(const float* __restrict__ s,
                                                    __bf16* __restrict__ d) {
  int i = blockIdx.x * 256 + threadIdx.x;   // < 8192 float4-groups
  bf16x4 o;
  if (i < 3840) {                            // 60*256/4
    float4 v = ((const float4*)s)[i];
    o[0] = (__bf16)v.x; o[1] = (__bf16)v.y; o[2] = (__bf16)v.z; o[3] = (__bf16)v.w;
  } else {
    o[0] = (__bf16)0.f; o[1] = (__bf16)0.f; o[2] = (__bf16)0.f; o[3] = (__bf16)0.f;
  }
  ((bf16x4*)d)[i] = o;
}

// ---------------- K1: causal depthwise conv (k=3) + residual + LN -> bf16 ---
__global__ __launch_bounds__(256) void conv_ln_kernel(
    const float* __restrict__ x, const float* __restrict__ cw,
    const float* __restrict__ cb, const float* __restrict__ g,
    const float* __restrict__ bta, __bf16* __restrict__ xn) {
  int row = blockIdx.x;            // b*L + l
  int l = row & (LL - 1);
  const float* xr = x + (size_t)row * DD;
  __shared__ float red[16];
  float vals[3];
  float s = 0.f, ss = 0.f;
#pragma unroll
  for (int i = 0; i < 3; i++) {
    int d = threadIdx.x + i * 256;
    float x0 = xr[d];
    float xm1 = (l >= 1) ? xr[d - DD] : 0.f;
    float xm2 = (l >= 2) ? xr[d - 2 * DD] : 0.f;
    float c = xm2 * cw[d * 3 + 0] + xm1 * cw[d * 3 + 1] + x0 * cw[d * 3 + 2] + cb[d];
    float v = x0 + c;
    vals[i] = v; s += v; ss += v * v;
  }
  s = wave_sum64(s); ss = wave_sum64(ss);
  int wid = threadIdx.x >> 6;
  if ((threadIdx.x & 63) == 0) { red[wid * 2] = s; red[wid * 2 + 1] = ss; }
  __syncthreads();
  if (threadIdx.x == 0) {
    red[8] = red[0] + red[2] + red[4] + red[6];
    red[9] = red[1] + red[3] + red[5] + red[7];
  }
  __syncthreads();
  float mu = red[8] * (1.f / 768.f);
  float var = red[9] * (1.f / 768.f) - mu * mu;
  float inv = rsqrtf(var + 1e-5f);
  __bf16* xo = xn + (size_t)row * DD;
#pragma unroll
  for (int i = 0; i < 3; i++) {
    int d = threadIdx.x + i * 256;
    xo[d] = (__bf16)((vals[i] - mu) * inv * g[d] + bta[d]);
  }
}

// ---------------- K2: bf16 MFMA GEMM  C = A(M,K) * B(N,K)^T + bias ----------
// MODE 0: none; MODE 1: qkv epilogue (elu+1 on n<1536); MODE 2: silu
template <int MODE, bool HASBIAS, bool OUTBF>
__global__ __launch_bounds__(256) void gemm_mfma_kernel(
    const __bf16* __restrict__ A, const __bf16* __restrict__ Bw,
    const float* __restrict__ bias, void* __restrict__ Cv,
    int M, int N, int K) {
  __shared__ __attribute__((aligned(16))) __bf16 As[128 * 64];
  __shared__ __attribute__((aligned(16))) __bf16 Bs[128 * 64];
  int m0 = blockIdx.y * 128, n0 = blockIdx.x * 128;
  int tid = threadIdx.x;
  int w = tid >> 6, lane = tid & 63;
  int wm = w >> 1, wn = w & 1;          // wave grid 2x2, each wave 64x64
  int quad = lane >> 4, l16 = lane & 15;

  int lrow = lane >> 3;                  // 0..7 row within wave-call
  int lchunk = (lane & 7) ^ lrow;        // swizzled source chunk
  int R0 = w * 8;

  floatx4 acc[4][4];
#pragma unroll
  for (int i = 0; i < 4; i++)
#pragma unroll
    for (int j = 0; j < 4; j++) acc[i][j] = (floatx4)0.f;

  for (int k0 = 0; k0 < K; k0 += 64) {
    __syncthreads();
#pragma unroll
    for (int r = 0; r < 4; r++) {
      int row = r * 32 + R0 + lrow;
      gl_lds16(A + (size_t)(m0 + row) * K + k0 + lchunk * 8, &As[(r * 32 + R0) * 64]);
      gl_lds16(Bw + (size_t)(n0 + row) * K + k0 + lchunk * 8, &Bs[(r * 32 + R0) * 64]);
    }
    __syncthreads();
#pragma unroll
    for (int s = 0; s < 2; s++) {
      bf16x8 af[4], bfr[4];
      int csw = (s << 2) + quad;
#pragma unroll
      for (int i = 0; i < 4; i++) {
        int m = wm * 64 + i * 16 + l16;
        af[i] = *(const bf16x8*)&As[m * 64 + (csw ^ (l16 & 7)) * 8];
      }
#pragma unroll
      for (int j = 0; j < 4; j++) {
        int n = wn * 64 + j * 16 + l16;
        bfr[j] = *(const bf16x8*)&Bs[n * 64 + (csw ^ (l16 & 7)) * 8];
      }
#pragma unroll
      for (int i = 0; i < 4; i++)
#pragma unroll
        for (int j = 0; j < 4; j++)
          acc[i][j] = __builtin_amdgcn_mfma_f32_16x16x32_bf16(af[i], bfr[j], acc[i][j], 0, 0, 0);
    }
  }
#pragma unroll
  for (int j = 0; j < 4; j++) {
    int gcol = n0 + wn * 64 + j * 16 + l16;
    float bv = HASBIAS ? bias[gcol] : 0.f;
#pragma unroll
    for (int i = 0; i < 4; i++) {
      int grow = m0 + wm * 64 + i * 16 + quad * 4;
#pragma unroll
      for (int r = 0; r < 4; r++) {
        float v = acc[i][j][r] + bv;
        if (MODE == 1) { if (gcol < 1536) v = (v > 0.f) ? v + 1.f : expf(v); }
        if (MODE == 2) { v = v / (1.f + expf(-v)); }
        if (OUTBF) ((__bf16*)Cv)[(size_t)(grow + r) * N + gcol] = (__bf16)v;
        else       ((float*)Cv)[(size_t)(grow + r) * N + gcol] = v;
      }
    }
  }
}

// ---------------- K3: param transforms from pp (2048x128) -> gate, decay ----
__global__ __launch_bounds__(256) void params_transform(
    const float* __restrict__ pp, const float* __restrict__ temp,
    float* __restrict__ gate, float* __restrict__ dec) {
  int g = blockIdx.x * 256 + threadIdx.x;   // < 24576 = 2048*12
  int row = g / 12;
  int h = g - row * 12;
  const float* p = pp + (size_t)row * 128 + h * 5;
  float p0 = p[0], p1 = p[1], p2 = p[2], p3 = p[3], p4 = p[4];
  const float PI = 3.14159265358979323846f;
  float sa = sigm(p0);
  float sp = tanhf(p1) * PI;
  float ca = sigm(p2);
  float cp = tanhf(p3) * PI;
  float dc = 0.3f + 0.65f * sigm(p4);
  float gt = sigm(sa * ca * cosf(sp - cp) * temp[0]);
  gate[g] = gt;                             // g == row*HH + h
  int b = row >> 10, l = row & 1023;
  dec[((b * HH + h) << 10) + l] = dc;       // (B,H,L)
}

// ---------------- K4: df = exp(cumsum(log decay)) per (b,h) -----------------
__global__ __launch_bounds__(64) void df_kernel(const float* __restrict__ dec,
                                                float* __restrict__ df) {
  int bh = blockIdx.x;
  int lane = threadIdx.x;
  const float* dp = dec + (size_t)bh * LL + lane * 16;
  double ls[16];
  double s = 0.0;
#pragma unroll
  for (int i = 0; i < 16; i++) { s += (double)logf(dp[i]); ls[i] = s; }
  double tot = s;
  double run = tot;
#pragma unroll
  for (int off = 1; off < 64; off <<= 1) {
    double n = __shfl_up(run, off, 64);
    if (lane >= off) run += n;
  }
  double excl = run - tot;
  float* dfo = df + (size_t)bh * LL + lane * 16;
#pragma unroll
  for (int i = 0; i < 16; i++) dfo[i] = expf((float)(excl + ls[i]));
}

// ---------------- K5: scan phase1 — d-split, 4 waves/block ------------------
// wave w owns KV rows [16w,16w+16); lane e = column
__global__ __launch_bounds__(256) void scan_phase1(
    const float* __restrict__ qkv, const float* __restrict__ dec,
    const float* __restrict__ df, const float* __restrict__ gate,
    float* __restrict__ kvcs, float* __restrict__ zcs, float* __restrict__ Aarr) {
  int blk = blockIdx.x;            // bh*NC + c
  int bh = blk >> 6, c = blk & (NC - 1);
  int b = bh / HH, h = bh - b * HH;
  int tid = threadIdx.x;
  int w = tid >> 6, e = tid & 63;
  int t0 = c * CL;
  __shared__ float kbuf[CL][64];
  __shared__ float vbuf[CL][64];
  __shared__ float sbuf[CL][4];
  const float* base = qkv + ((size_t)(b * LL + t0)) * 2304 + h * 64;
  // stage k (rows 0-15) and v (rows 16-31), 16 rows/round, float4 per thread
#pragma unroll
  for (int r = 0; r < 2; r++) {
    int row = r * 16 + (tid >> 4);
    int sec = row >> 4;              // 0:k 1:v
    int t = row & 15;
    int col = (tid & 15) << 2;
    float4 vv = *(const float4*)(base + (size_t)t * 2304 + (sec + 1) * 768 + col);
    float* dst = (sec == 0) ? &kbuf[t][col] : &vbuf[t][col];
    *(float4*)dst = vv;
  }
  if (tid < CL) {
    int t = t0 + tid;
    float a = dec[bh * LL + t];
    float d = df[bh * LL + t];
    float r = d / (d + 1e-8f);
    float g = gate[(b * LL + t) * HH + h];
    sbuf[tid][0] = a; sbuf[tid][1] = r; sbuf[tid][2] = g * (1.f - a);
    sbuf[tid][3] = (1.f - a) * r;
  }
  __syncthreads();
  float KV[16];
#pragma unroll
  for (int d = 0; d < 16; d++) KV[d] = 0.f;
  float z = 0.f, A = 1.f;
  for (int t = 0; t < CL; t++) {
    float a = sbuf[t][0], r = sbuf[t][1], cs = sbuf[t][2], w1r = sbuf[t][3];
    float vc = vbuf[t][e] * cs;
    A *= a;
#pragma unroll
    for (int d4 = 0; d4 < 4; d4++) {
      float4 k4 = *(const float4*)&kbuf[t][(w << 4) + (d4 << 2)];
      float kr[4] = {k4.x, k4.y, k4.z, k4.w};
#pragma unroll
      for (int j = 0; j < 4; j++) {
        float u = fminf(fmaxf(kr[j] * vc, -5.f), 5.f);
        KV[(d4 << 2) + j] = fmaf(a, KV[(d4 << 2) + j], r * u);
      }
    }
    z = fmaf(a, z, kbuf[t][e] * w1r);
  }
  float* kvo = kvcs + (size_t)blk * 4096 + (w << 4) * 64 + e;
#pragma unroll
  for (int d = 0; d < 16; d++) kvo[d * 64] = KV[d];
  if (w == 0) zcs[blk * 64 + e] = z;
  if (tid == 0) Aarr[blk] = A;
}

// ---------------- K6: sequential carry combine (in-place end->init) ---------
__global__ __launch_bounds__(256) void combine_kernel(
    const float* __restrict__ Aarr, float* __restrict__ kv, float* __restrict__ z) {
  int g = blockIdx.x * 256 + threadIdx.x;
  if (g < NBH * 4096) {
    int bh = g >> 12, idx = g & 4095;
    const float* Ap = Aarr + bh * NC;
    float* p = kv + (size_t)bh * NC * 4096 + idx;
    float carry = 0.f;
#pragma unroll 8
    for (int c = 0; c < NC; c++) {
      float endv = p[(size_t)c * 4096];
      p[(size_t)c * 4096] = carry;          // init state for chunk c
      carry = fmaf(Ap[c], carry, endv);     // state entering chunk c+1
    }
  } else {
    int g2 = g - NBH * 4096;
    int bh = g2 >> 6, idx = g2 & 63;
    const float* Ap = Aarr + bh * NC;
    float* p = z + bh * NC * 64 + idx;
    float carry = 0.f;
#pragma unroll 8
    for (int c = 0; c < NC; c++) {
      float endv = p[c * 64];
      p[c * 64] = carry;
      carry = fmaf(Ap[c], carry, endv);
    }
  }
}

// ---------------- K7: scan phase3 — d-split replay + den + head LN -> bf16 --
__global__ __launch_bounds__(256) void scan_phase3(
    const float* __restrict__ qkv, const float* __restrict__ dec,
    const float* __restrict__ df, const float* __restrict__ gate,
    const float* __restrict__ kvcs, const float* __restrict__ zcs,
    const float* __restrict__ mng, const float* __restrict__ mnb,
    __bf16* __restrict__ att) {
  int blk = blockIdx.x;
  int bh = blk >> 6, c = blk & (NC - 1);
  int b = bh / HH, h = bh - b * HH;
  int tid = threadIdx.x;
  int w = tid >> 6, e = tid & 63;
  int t0 = c * CL;
  __shared__ float qbuf[CL][64];
  __shared__ float kbuf[CL][64];
  __shared__ float vbuf[CL][64];
  __shared__ float sbuf[CL][4];
  __shared__ float pbuf[2][4][64];
  const float* base = qkv + ((size_t)(b * LL + t0)) * 2304 + h * 64;
#pragma unroll
  for (int r = 0; r < 3; r++) {
    int row = r * 16 + (tid >> 4);
    int sec = row >> 4;              // 0:q 1:k 2:v
    int t = row & 15;
    int col = (tid & 15) << 2;
    float4 vv = *(const float4*)(base + (size_t)t * 2304 + sec * 768 + col);
    float* dst = (sec == 0) ? &qbuf[t][col] : (sec == 1) ? &kbuf[t][col] : &vbuf[t][col];
    *(float4*)dst = vv;
  }
  if (tid < CL) {
    int t = t0 + tid;
    float a = dec[bh * LL + t];
    float d = df[bh * LL + t];
    float r = d / (d + 1e-8f);
    float g = gate[(b * LL + t) * HH + h];
    sbuf[tid][0] = a; sbuf[tid][1] = r; sbuf[tid][2] = g * (1.f - a);
    sbuf[tid][3] = (1.f - a) * r;
  }
  float KV[16];
  const float* kvi = kvcs + (size_t)blk * 4096 + (w << 4) * 64 + e;
#pragma unroll
  for (int d = 0; d < 16; d++) KV[d] = kvi[d * 64];
  float z = zcs[blk * 64 + e];      // replicated in every wave
  float mg = mng[e], mb = mnb[e];
  __syncthreads();
  for (int t = 0; t < CL; t++) {
    float a = sbuf[t][0], r = sbuf[t][1], cs = sbuf[t][2], w1r = sbuf[t][3];
    float vc = vbuf[t][e] * cs;
    float onp = 0.f;
#pragma unroll
    for (int d4 = 0; d4 < 4; d4++) {
      float4 k4 = *(const float4*)&kbuf[t][(w << 4) + (d4 << 2)];
      float4 q4 = *(const float4*)&qbuf[t][(w << 4) + (d4 << 2)];
      float kr[4] = {k4.x, k4.y, k4.z, k4.w};
      float qr[4] = {q4.x, q4.y, q4.z, q4.w};
#pragma unroll
      for (int j = 0; j < 4; j++) {
        float u = fminf(fmaxf(kr[j] * vc, -5.f), 5.f);
        float nv = fmaf(a, KV[(d4 << 2) + j], r * u);
        KV[(d4 << 2) + j] = nv;
        onp = fmaf(qr[j], nv, onp);
      }
    }
    pbuf[t & 1][w][e] = onp;
    z = fmaf(a, z, kbuf[t][e] * w1r);
    __syncthreads();
    if (w == (t & 3)) {             // rotating reducer wave
      float on = pbuf[t & 1][0][e] + pbuf[t & 1][1][e] +
                 pbuf[t & 1][2][e] + pbuf[t & 1][3][e];
      float zc = fminf(fmaxf(z, -10000.f), 10000.f);
      float qe = qbuf[t][e];
      float s0 = qe * zc, s1 = on, s2 = on * on;
#pragma unroll
      for (int off = 32; off; off >>= 1) {
        s0 += __shfl_xor(s0, off, 64);
        s1 += __shfl_xor(s1, off, 64);
        s2 += __shfl_xor(s2, off, 64);
      }
      float den = s0 + 1e-4f;
      float idn = 1.f / den;
      float o = on * idn;
      float mu = s1 * idn * (1.f / 64.f);
      float E2 = s2 * idn * idn * (1.f / 64.f);
      float var = E2 - mu * mu;
      float outv = (o - mu) * rsqrtf(var + 1e-5f) * mg + mb;
      att[((size_t)(b * LL + t0 + t)) * DD + h * 64 + e] = (__bf16)outv;
    }
  }
}

// ---------------------------------------------------------------------------
extern "C" void kernel_launch(void* const* d_in, const int* in_sizes, int n_in,
                              void* d_out, int out_size, void* d_ws, size_t ws_size,
                              hipStream_t stream) {
  (void)in_sizes; (void)n_in; (void)out_size; (void)ws_size;
  const float* x           = (const float*)d_in[0];
  const float* conv_w      = (const float*)d_in[1];
  const float* conv_b      = (const float*)d_in[2];
  const float* ln_g        = (const float*)d_in[3];
  const float* ln_b        = (const float*)d_in[4];
  const float* qkv_w       = (const float*)d_in[5];
  const float* qkv_b       = (const float*)d_in[6];
  const float* bn_w1       = (const float*)d_in[7];
  const float* bn_w2       = (const float*)d_in[8];
  const float* temperature = (const float*)d_in[9];
  const float* proj_w      = (const float*)d_in[10];
  const float* proj_b      = (const float*)d_in[11];
  const float* mn_g        = (const float*)d_in[12];
  const float* mn_b        = (const float*)d_in[13];

  float* y    = (float*)d_out;
  float* gate = y + 2 * 1024 * 768;      // outputs concatenated: y then gate

  char* ws = (char*)d_ws;
  __bf16* xn_bf   = (__bf16*)(ws);                // 3.15 MB, reused as att_bf
  __bf16* att_bf  = xn_bf;                        // alias (xn dead before phase3)
  float*  qkva    = (float*)(ws + 3145728);       // 18.87 MB
  __bf16* hbuf_bf = (__bf16*)(ws + 22020096);     // 1.05 MB (2048x256 bf16)
  float*  pp      = (float*)(ws + 23068672);      // 1.05 MB (2048x128 fp32)
  float*  dec     = (float*)(ws + 24117248);      // 96 KB  (B,H,L)
  float*  dfb     = (float*)(ws + 24215552);      // 96 KB
  float*  kvcs    = (float*)(ws + 24313856);      // 25.17 MB (end->init in place)
  __bf16* qkvw_bf = (__bf16*)(ws + 24313856);     // 3.54 MB alias (dead before phase1)
  float*  zcs     = (float*)(ws + 49479680);      // 384 KB
  float*  Aarr    = (float*)(ws + 49872896);      // 6 KB
  __bf16* bnw1_bf = (__bf16*)(ws + 49879040);     // 0.39 MB
  __bf16* projw_bf= (__bf16*)(ws + 50272256);     // 1.18 MB
  __bf16* w2p_bf  = (__bf16*)(ws + 51451904);     // 64 KB  -> total 51.5 MB

  // weight converts (fp32 -> bf16)
  f2bf_kernel<<<1728, 256, 0, stream>>>(qkv_w, qkvw_bf, 442368);
  f2bf_kernel<<<192, 256, 0, stream>>>(bn_w1, bnw1_bf, 49152);
  f2bf_kernel<<<576, 256, 0, stream>>>(proj_w, projw_bf, 147456);
  w2pad_kernel<<<32, 256, 0, stream>>>(bn_w2, w2p_bf);

  conv_ln_kernel<<<2048, 256, 0, stream>>>(x, conv_w, conv_b, ln_g, ln_b, xn_bf);

  // qkv = xn @ qkv_w.T + b, with elu+1 on q,k in the epilogue
  gemm_mfma_kernel<1, true, false><<<dim3(18, 16), 256, 0, stream>>>(
      xn_bf, qkvw_bf, qkv_b, qkva, 2048, 2304, 768);

  // h = silu(xn @ bn_w1.T)  -> bf16
  gemm_mfma_kernel<2, false, true><<<dim3(2, 16), 256, 0, stream>>>(
      xn_bf, bnw1_bf, nullptr, hbuf_bf, 2048, 256, 768);

  // pp = h @ w2p.T  (N=128, rows>=60 are zero-padded)
  gemm_mfma_kernel<0, false, false><<<dim3(1, 16), 256, 0, stream>>>(
      hbuf_bf, w2p_bf, nullptr, pp, 2048, 128, 256);

  params_transform<<<96, 256, 0, stream>>>(pp, temperature, gate, dec);

  df_kernel<<<NBH, 64, 0, stream>>>(dec, dfb);

  scan_phase1<<<NBH * NC, 256, 0, stream>>>(qkva, dec, dfb, gate, kvcs, zcs, Aarr);

  combine_kernel<<<390, 256, 0, stream>>>(Aarr, kvcs, zcs);

  scan_phase3<<<NBH * NC, 256, 0, stream>>>(qkva, dec, dfb, gate, kvcs, zcs,
                                            mn_g, mn_b, att_bf);

  // y = att @ proj_w.T + proj_b
  gemm_mfma_kernel<0, true, false><<<dim3(6, 16), 256, 0, stream>>>(
      att_bf, projw_bf, proj_b, y, 2048, 768, 768);
}

// Round 5
// 193.739 us; speedup vs baseline: 1.9156x; 1.1358x over previous
//
#include <hip/hip_runtime.h>
#include <math.h>

#define LL 1024
#define DD 768
#define HH 12
#define CL 16
#define NC 64   // LL / CL
#define NBH 24  // B*H

typedef __bf16 bf16x8 __attribute__((ext_vector_type(8)));
typedef __bf16 bf16x4 __attribute__((ext_vector_type(4)));
typedef float floatx4 __attribute__((ext_vector_type(4)));

typedef const void __attribute__((address_space(1)))* gas_ptr;
typedef void __attribute__((address_space(3)))* las_ptr;

__device__ __forceinline__ void gl_lds16(const void* g, void* s) {
  __builtin_amdgcn_global_load_lds((gas_ptr)g, (las_ptr)s, 16, 0, 0);
}

__device__ __forceinline__ float wave_sum64(float v) {
#pragma unroll
  for (int off = 32; off; off >>= 1) v += __shfl_xor(v, off, 64);
  return v;
}

__device__ __forceinline__ float sigm(float x) { return 1.0f / (1.0f + expf(-x)); }

// ---------------- K0: all weight converts fused (fp32 -> bf16) --------------
// ranges (float4 groups): qkv_w 442368 | bn_w1 49152 | proj_w 147456 | w2pad 8192
__global__ __launch_bounds__(256) void convert_all(
    const float* __restrict__ qkvw, const float* __restrict__ bnw1,
    const float* __restrict__ projw, const float* __restrict__ w2,
    __bf16* __restrict__ dq, __bf16* __restrict__ d1,
    __bf16* __restrict__ dp, __bf16* __restrict__ dw2) {
  int i = blockIdx.x * 256 + threadIdx.x;
  if (i >= 647168) return;
  if (i >= 638976) {                       // w2 pad region (128x256 bf16)
    int off = i - 638976;
    bf16x4 o;
    if (off < 3840) {                      // 60*256/4 real rows
      float4 v = ((const float4*)w2)[off];
      o[0] = (__bf16)v.x; o[1] = (__bf16)v.y; o[2] = (__bf16)v.z; o[3] = (__bf16)v.w;
    } else {
      o[0] = (__bf16)0.f; o[1] = (__bf16)0.f; o[2] = (__bf16)0.f; o[3] = (__bf16)0.f;
    }
    ((bf16x4*)dw2)[off] = o;
    return;
  }
  const float* s; __bf16* d; int off;
  if (i < 442368)      { s = qkvw;  d = dq; off = i; }
  else if (i < 491520) { s = bnw1;  d = d1; off = i - 442368; }
  else                 { s = projw; d = dp; off = i - 491520; }
  float4 v = ((const float4*)s)[off];
  bf16x4 o;
  o[0] = (__bf16)v.x; o[1] = (__bf16)v.y; o[2] = (__bf16)v.z; o[3] = (__bf16)v.w;
  ((bf16x4*)d)[off] = o;
}

// ---------------- K1: causal depthwise conv (k=3) + residual + LN -> bf16 ---
__global__ __launch_bounds__(256) void conv_ln_kernel(
    const float* __restrict__ x, const float* __restrict__ cw,
    const float* __restrict__ cb, const float* __restrict__ g,
    const float* __restrict__ bta, __bf16* __restrict__ xn) {
  int row = blockIdx.x;            // b*L + l
  int l = row & (LL - 1);
  const float* xr = x + (size_t)row * DD;
  __shared__ float red[16];
  float vals[3];
  float s = 0.f, ss = 0.f;
#pragma unroll
  for (int i = 0; i < 3; i++) {
    int d = threadIdx.x + i * 256;
    float x0 = xr[d];
    float xm1 = (l >= 1) ? xr[d - DD] : 0.f;
    float xm2 = (l >= 2) ? xr[d - 2 * DD] : 0.f;
    float c = xm2 * cw[d * 3 + 0] + xm1 * cw[d * 3 + 1] + x0 * cw[d * 3 + 2] + cb[d];
    float v = x0 + c;
    vals[i] = v; s += v; ss += v * v;
  }
  s = wave_sum64(s); ss = wave_sum64(ss);
  int wid = threadIdx.x >> 6;
  if ((threadIdx.x & 63) == 0) { red[wid * 2] = s; red[wid * 2 + 1] = ss; }
  __syncthreads();
  if (threadIdx.x == 0) {
    red[8] = red[0] + red[2] + red[4] + red[6];
    red[9] = red[1] + red[3] + red[5] + red[7];
  }
  __syncthreads();
  float mu = red[8] * (1.f / 768.f);
  float var = red[9] * (1.f / 768.f) - mu * mu;
  float inv = rsqrtf(var + 1e-5f);
  __bf16* xo = xn + (size_t)row * DD;
#pragma unroll
  for (int i = 0; i < 3; i++) {
    int d = threadIdx.x + i * 256;
    xo[d] = (__bf16)((vals[i] - mu) * inv * g[d] + bta[d]);
  }
}

// ---------------- K2: bf16 MFMA GEMM  C = A(M,K) * B(N,K)^T + bias ----------
// BM x 128 tile (BM=64 -> 2x block count for small shapes), BK=64,
// global_load_lds staging, XOR-swizzled LDS chunks.
// MODE 0: none; MODE 1: qkv epilogue (elu+1 on n<1536); MODE 2: silu
template <int BM, int MODE, bool HASBIAS, bool OUTBF>
__global__ __launch_bounds__(256) void gemm_mfma_kernel(
    const __bf16* __restrict__ A, const __bf16* __restrict__ Bw,
    const float* __restrict__ bias, void* __restrict__ Cv,
    int M, int N, int K) {
  constexpr int MI = BM / 32;            // per-wave 16-row tiles
  __shared__ __attribute__((aligned(16))) __bf16 As[BM * 64];
  __shared__ __attribute__((aligned(16))) __bf16 Bs[128 * 64];
  int m0 = blockIdx.y * BM, n0 = blockIdx.x * 128;
  int tid = threadIdx.x;
  int w = tid >> 6, lane = tid & 63;
  int wm = w >> 1, wn = w & 1;          // wave grid 2x2
  int quad = lane >> 4, l16 = lane & 15;

  int lrow = lane >> 3;                  // 0..7 row within wave-call
  int lchunk = (lane & 7) ^ lrow;        // swizzled source chunk
  int R0 = w * 8;

  floatx4 acc[MI][4];
#pragma unroll
  for (int i = 0; i < MI; i++)
#pragma unroll
    for (int j = 0; j < 4; j++) acc[i][j] = (floatx4)0.f;

  for (int k0 = 0; k0 < K; k0 += 64) {
    __syncthreads();
#pragma unroll
    for (int r = 0; r < BM / 32; r++) {
      int row = r * 32 + R0 + lrow;
      gl_lds16(A + (size_t)(m0 + row) * K + k0 + lchunk * 8, &As[(r * 32 + R0) * 64]);
    }
#pragma unroll
    for (int r = 0; r < 4; r++) {
      int row = r * 32 + R0 + lrow;
      gl_lds16(Bw + (size_t)(n0 + row) * K + k0 + lchunk * 8, &Bs[(r * 32 + R0) * 64]);
    }
    __syncthreads();
#pragma unroll
    for (int s = 0; s < 2; s++) {
      bf16x8 af[MI], bfr[4];
      int csw = (s << 2) + quad;
#pragma unroll
      for (int i = 0; i < MI; i++) {
        int m = wm * (BM / 2) + i * 16 + l16;
        af[i] = *(const bf16x8*)&As[m * 64 + (csw ^ (l16 & 7)) * 8];
      }
#pragma unroll
      for (int j = 0; j < 4; j++) {
        int n = wn * 64 + j * 16 + l16;
        bfr[j] = *(const bf16x8*)&Bs[n * 64 + (csw ^ (l16 & 7)) * 8];
      }
#pragma unroll
      for (int i = 0; i < MI; i++)
#pragma unroll
        for (int j = 0; j < 4; j++)
          acc[i][j] = __builtin_amdgcn_mfma_f32_16x16x32_bf16(af[i], bfr[j], acc[i][j], 0, 0, 0);
    }
  }
#pragma unroll
  for (int j = 0; j < 4; j++) {
    int gcol = n0 + wn * 64 + j * 16 + l16;
    float bv = HASBIAS ? bias[gcol] : 0.f;
#pragma unroll
    for (int i = 0; i < MI; i++) {
      int grow = m0 + wm * (BM / 2) + i * 16 + quad * 4;
#pragma unroll
      for (int r = 0; r < 4; r++) {
        float v = acc[i][j][r] + bv;
        if (MODE == 1) { if (gcol < 1536) v = (v > 0.f) ? v + 1.f : expf(v); }
        if (MODE == 2) { v = v / (1.f + expf(-v)); }
        if (OUTBF) ((__bf16*)Cv)[(size_t)(grow + r) * N + gcol] = (__bf16)v;
        else       ((float*)Cv)[(size_t)(grow + r) * N + gcol] = v;
      }
    }
  }
}

// ---------------- K3: params transform + df (fused, one block per bh) -------
__global__ __launch_bounds__(256) void params_df_kernel(
    const float* __restrict__ pp, const float* __restrict__ temp,
    float* __restrict__ gate, float* __restrict__ dec, float* __restrict__ dfb) {
  int bh = blockIdx.x;             // < 24
  int b = bh / HH, h = bh - b * HH;
  int tid = threadIdx.x;
  int lane = tid & 63, wid = tid >> 6;
  float tv = temp[0];
  const float PI = 3.14159265358979323846f;
  double ls[4];
  double lsum = 0.0;
#pragma unroll
  for (int i = 0; i < 4; i++) {
    int l = tid * 4 + i;
    int row = (b << 10) + l;
    const float* p = pp + (size_t)row * 128 + h * 5;
    float p0 = p[0], p1 = p[1], p2 = p[2], p3 = p[3], p4 = p[4];
    float sa = sigm(p0);
    float sp = tanhf(p1) * PI;
    float ca = sigm(p2);
    float cp = tanhf(p3) * PI;
    float dc = 0.3f + 0.65f * sigm(p4);
    float gt = sigm(sa * ca * cosf(sp - cp) * tv);
    gate[row * HH + h] = gt;
    dec[(bh << 10) + l] = dc;
    lsum += (double)logf(dc);
    ls[i] = lsum;
  }
  // inclusive scan of per-thread lsum within wave
  double run = lsum;
#pragma unroll
  for (int off = 1; off < 64; off <<= 1) {
    double n = __shfl_up(run, off, 64);
    if (lane >= off) run += n;
  }
  __shared__ double wsum[4];
  if (lane == 63) wsum[wid] = run;
  __syncthreads();
  double wexcl = 0.0;
  for (int k = 0; k < wid; k++) wexcl += wsum[k];
  double excl = wexcl + run - lsum;        // exclusive prefix for this thread
  float* dfo = dfb + (bh << 10) + tid * 4;
#pragma unroll
  for (int i = 0; i < 4; i++) dfo[i] = expf((float)(excl + ls[i]));
}

// ---------------- K5: scan phase1 — d-split, 4 waves/block ------------------
// wave w owns KV rows [16w,16w+16); lane e = column
__global__ __launch_bounds__(256) void scan_phase1(
    const float* __restrict__ qkv, const float* __restrict__ dec,
    const float* __restrict__ df, const float* __restrict__ gate,
    float* __restrict__ kvcs, float* __restrict__ zcs, float* __restrict__ Aarr) {
  int blk = blockIdx.x;            // bh*NC + c
  int bh = blk >> 6, c = blk & (NC - 1);
  int b = bh / HH, h = bh - b * HH;
  int tid = threadIdx.x;
  int w = tid >> 6, e = tid & 63;
  int t0 = c * CL;
  __shared__ __attribute__((aligned(16))) float kbuf[CL][64];
  __shared__ __attribute__((aligned(16))) float vbuf[CL][64];
  __shared__ float sbuf[CL][4];
  const float* base = qkv + ((size_t)(b * LL + t0)) * 2304 + h * 64;
  // async stage: wave w stages k rows 4w..4w+3 and v rows 4w..4w+3
  {
    int t = (w << 2) + (e >> 4);
    int col = (e & 15) << 2;
    gl_lds16(base + (size_t)t * 2304 + 768 + col, &kbuf[w << 2][0]);
    gl_lds16(base + (size_t)t * 2304 + 1536 + col, &vbuf[w << 2][0]);
  }
  if (tid < CL) {
    int t = t0 + tid;
    float a = dec[bh * LL + t];
    float d = df[bh * LL + t];
    float r = d / (d + 1e-8f);
    float g = gate[(b * LL + t) * HH + h];
    sbuf[tid][0] = a; sbuf[tid][1] = r; sbuf[tid][2] = g * (1.f - a);
    sbuf[tid][3] = (1.f - a) * r;
  }
  __syncthreads();
  float KV[16];
#pragma unroll
  for (int d = 0; d < 16; d++) KV[d] = 0.f;
  float z = 0.f, A = 1.f;
  for (int t = 0; t < CL; t++) {
    float a = sbuf[t][0], r = sbuf[t][1], cs = sbuf[t][2], w1r = sbuf[t][3];
    float vc = vbuf[t][e] * cs;
    A *= a;
#pragma unroll
    for (int d4 = 0; d4 < 4; d4++) {
      float4 k4 = *(const float4*)&kbuf[t][(w << 4) + (d4 << 2)];
      float kr[4] = {k4.x, k4.y, k4.z, k4.w};
#pragma unroll
      for (int j = 0; j < 4; j++) {
        float u = fminf(fmaxf(kr[j] * vc, -5.f), 5.f);
        KV[(d4 << 2) + j] = fmaf(a, KV[(d4 << 2) + j], r * u);
      }
    }
    z = fmaf(a, z, kbuf[t][e] * w1r);
  }
  float* kvo = kvcs + (size_t)blk * 4096 + (w << 4) * 64 + e;
#pragma unroll
  for (int d = 0; d < 16; d++) kvo[d * 64] = KV[d];
  if (w == 0) zcs[blk * 64 + e] = z;
  if (tid == 0) Aarr[blk] = A;
}

// ---------------- K6: sequential carry combine (in-place end->init) ---------
__global__ __launch_bounds__(256) void combine_kernel(
    const float* __restrict__ Aarr, float* __restrict__ kv, float* __restrict__ z) {
  int g = blockIdx.x * 256 + threadIdx.x;
  if (g < NBH * 4096) {
    int bh = g >> 12, idx = g & 4095;
    const float* Ap = Aarr + bh * NC;
    float* p = kv + (size_t)bh * NC * 4096 + idx;
    float carry = 0.f;
#pragma unroll 8
    for (int c = 0; c < NC; c++) {
      float endv = p[(size_t)c * 4096];
      p[(size_t)c * 4096] = carry;          // init state for chunk c
      carry = fmaf(Ap[c], carry, endv);     // state entering chunk c+1
    }
  } else {
    int g2 = g - NBH * 4096;
    int bh = g2 >> 6, idx = g2 & 63;
    const float* Ap = Aarr + bh * NC;
    float* p = z + bh * NC * 64 + idx;
    float carry = 0.f;
#pragma unroll 8
    for (int c = 0; c < NC; c++) {
      float endv = p[c * 64];
      p[c * 64] = carry;
      carry = fmaf(Ap[c], carry, endv);
    }
  }
}

// ---------------- K7: scan phase3 — barrier-free t-loop, batched epilogue ---
__global__ __launch_bounds__(256) void scan_phase3(
    const float* __restrict__ qkv, const float* __restrict__ dec,
    const float* __restrict__ df, const float* __restrict__ gate,
    const float* __restrict__ kvcs, const float* __restrict__ zcs,
    const float* __restrict__ mng, const float* __restrict__ mnb,
    __bf16* __restrict__ att) {
  int blk = blockIdx.x;
  int bh = blk >> 6, c = blk & (NC - 1);
  int b = bh / HH, h = bh - b * HH;
  int tid = threadIdx.x;
  int w = tid >> 6, e = tid & 63;
  int t0 = c * CL;
  __shared__ __attribute__((aligned(16))) float qbuf[CL][64];
  __shared__ __attribute__((aligned(16))) float kbuf[CL][64];
  __shared__ __attribute__((aligned(16))) float vbuf[CL][64];
  __shared__ float sbuf[CL][4];
  __shared__ float pbuf[CL][4][64];
  const float* base = qkv + ((size_t)(b * LL + t0)) * 2304 + h * 64;
  // async stage: wave w stages q,k,v rows 4w..4w+3
  {
    int t = (w << 2) + (e >> 4);
    int col = (e & 15) << 2;
    gl_lds16(base + (size_t)t * 2304 + col, &qbuf[w << 2][0]);
    gl_lds16(base + (size_t)t * 2304 + 768 + col, &kbuf[w << 2][0]);
    gl_lds16(base + (size_t)t * 2304 + 1536 + col, &vbuf[w << 2][0]);
  }
  if (tid < CL) {
    int t = t0 + tid;
    float a = dec[bh * LL + t];
    float d = df[bh * LL + t];
    float r = d / (d + 1e-8f);
    float g = gate[(b * LL + t) * HH + h];
    sbuf[tid][0] = a; sbuf[tid][1] = r; sbuf[tid][2] = g * (1.f - a);
    sbuf[tid][3] = (1.f - a) * r;
  }
  float KV[16];
  const float* kvi = kvcs + (size_t)blk * 4096 + (w << 4) * 64 + e;
#pragma unroll
  for (int d = 0; d < 16; d++) KV[d] = kvi[d * 64];
  float z = zcs[blk * 64 + e];      // replicated in every wave
  float zsnap[4];
  __syncthreads();
  for (int t = 0; t < CL; t++) {
    float a = sbuf[t][0], r = sbuf[t][1], cs = sbuf[t][2], w1r = sbuf[t][3];
    float vc = vbuf[t][e] * cs;
    float onp = 0.f;
#pragma unroll
    for (int d4 = 0; d4 < 4; d4++) {
      float4 k4 = *(const float4*)&kbuf[t][(w << 4) + (d4 << 2)];
      float4 q4 = *(const float4*)&qbuf[t][(w << 4) + (d4 << 2)];
      float kr[4] = {k4.x, k4.y, k4.z, k4.w};
      float qr[4] = {q4.x, q4.y, q4.z, q4.w};
#pragma unroll
      for (int j = 0; j < 4; j++) {
        float u = fminf(fmaxf(kr[j] * vc, -5.f), 5.f);
        float nv = fmaf(a, KV[(d4 << 2) + j], r * u);
        KV[(d4 << 2) + j] = nv;
        onp = fmaf(qr[j], nv, onp);
      }
    }
    pbuf[t][w][e] = onp;
    z = fmaf(a, z, kbuf[t][e] * w1r);
    if ((t >> 2) == w) zsnap[t & 3] = z;
  }
  __syncthreads();
  // wave w reduces t = 4w .. 4w+3
  float mg = mng[e], mb = mnb[e];
#pragma unroll
  for (int i = 0; i < 4; i++) {
    int t = (w << 2) + i;
    float on = pbuf[t][0][e] + pbuf[t][1][e] + pbuf[t][2][e] + pbuf[t][3][e];
    float zc = fminf(fmaxf(zsnap[i], -10000.f), 10000.f);
    float qe = qbuf[t][e];
    float s0 = qe * zc, s1 = on, s2 = on * on;
#pragma unroll
    for (int off = 32; off; off >>= 1) {
      s0 += __shfl_xor(s0, off, 64);
      s1 += __shfl_xor(s1, off, 64);
      s2 += __shfl_xor(s2, off, 64);
    }
    float den = s0 + 1e-4f;
    float idn = 1.f / den;
    float o = on * idn;
    float mu = s1 * idn * (1.f / 64.f);
    float E2 = s2 * idn * idn * (1.f / 64.f);
    float var = E2 - mu * mu;
    float outv = (o - mu) * rsqrtf(var + 1e-5f) * mg + mb;
    att[((size_t)(b * LL + t0 + t)) * DD + h * 64 + e] = (__bf16)outv;
  }
}

// ---------------------------------------------------------------------------
extern "C" void kernel_launch(void* const* d_in, const int* in_sizes, int n_in,
                              void* d_out, int out_size, void* d_ws, size_t ws_size,
                              hipStream_t stream) {
  (void)in_sizes; (void)n_in; (void)out_size; (void)ws_size;
  const float* x           = (const float*)d_in[0];
  const float* conv_w      = (const float*)d_in[1];
  const float* conv_b      = (const float*)d_in[2];
  const float* ln_g        = (const float*)d_in[3];
  const float* ln_b        = (const float*)d_in[4];
  const float* qkv_w       = (const float*)d_in[5];
  const float* qkv_b       = (const float*)d_in[6];
  const float* bn_w1       = (const float*)d_in[7];
  const float* bn_w2       = (const float*)d_in[8];
  const float* temperature = (const float*)d_in[9];
  const float* proj_w      = (const float*)d_in[10];
  const float* proj_b      = (const float*)d_in[11];
  const float* mn_g        = (const float*)d_in[12];
  const float* mn_b        = (const float*)d_in[13];

  float* y    = (float*)d_out;
  float* gate = y + 2 * 1024 * 768;      // outputs concatenated: y then gate

  char* ws = (char*)d_ws;
  __bf16* xn_bf   = (__bf16*)(ws);                // 3.15 MB, reused as att_bf
  __bf16* att_bf  = xn_bf;                        // alias (xn dead before phase3)
  float*  qkva    = (float*)(ws + 3145728);       // 18.87 MB
  __bf16* hbuf_bf = (__bf16*)(ws + 22020096);     // 1.05 MB (2048x256 bf16)
  float*  pp      = (float*)(ws + 23068672);      // 1.05 MB (2048x128 fp32)
  float*  dec     = (float*)(ws + 24117248);      // 96 KB  (B,H,L)
  float*  dfb     = (float*)(ws + 24215552);      // 96 KB
  float*  kvcs    = (float*)(ws + 24313856);      // 25.17 MB (end->init in place)
  __bf16* qkvw_bf = (__bf16*)(ws + 24313856);     // 3.54 MB alias (dead before phase1)
  float*  zcs     = (float*)(ws + 49479680);      // 384 KB
  float*  Aarr    = (float*)(ws + 49872896);      // 6 KB
  __bf16* bnw1_bf = (__bf16*)(ws + 49879040);     // 0.39 MB
  __bf16* projw_bf= (__bf16*)(ws + 50272256);     // 1.18 MB
  __bf16* w2p_bf  = (__bf16*)(ws + 51451904);     // 64 KB  -> total 51.5 MB

  convert_all<<<2528, 256, 0, stream>>>(qkv_w, bn_w1, proj_w, bn_w2,
                                        qkvw_bf, bnw1_bf, projw_bf, w2p_bf);

  conv_ln_kernel<<<2048, 256, 0, stream>>>(x, conv_w, conv_b, ln_g, ln_b, xn_bf);

  // qkv = xn @ qkv_w.T + b, with elu+1 on q,k in the epilogue
  gemm_mfma_kernel<64, 1, true, false><<<dim3(18, 32), 256, 0, stream>>>(
      xn_bf, qkvw_bf, qkv_b, qkva, 2048, 2304, 768);

  // h = silu(xn @ bn_w1.T)  -> bf16
  gemm_mfma_kernel<64, 2, false, true><<<dim3(2, 32), 256, 0, stream>>>(
      xn_bf, bnw1_bf, nullptr, hbuf_bf, 2048, 256, 768);

  // pp = h @ w2p.T  (N=128, rows>=60 are zero-padded)
  gemm_mfma_kernel<64, 0, false, false><<<dim3(1, 32), 256, 0, stream>>>(
      hbuf_bf, w2p_bf, nullptr, pp, 2048, 128, 256);

  params_df_kernel<<<NBH, 256, 0, stream>>>(pp, temperature, gate, dec, dfb);

  scan_phase1<<<NBH * NC, 256, 0, stream>>>(qkva, dec, dfb, gate, kvcs, zcs, Aarr);

  combine_kernel<<<390, 256, 0, stream>>>(Aarr, kvcs, zcs);

  scan_phase3<<<NBH * NC, 256, 0, stream>>>(qkva, dec, dfb, gate, kvcs, zcs,
                                            mn_g, mn_b, att_bf);

  // y = att @ proj_w.T + proj_b
  gemm_mfma_kernel<64, 0, true, false><<<dim3(6, 32), 256, 0, stream>>>(
      att_bf, projw_bf, proj_b, y, 2048, 768, 768);
}

// Round 7
// 176.081 us; speedup vs baseline: 2.1077x; 1.1003x over previous
//
#include <hip/hip_runtime.h>
#include <math.h>

#define LL 1024
#define DD 768
#define HH 12
#define CL 16
#define NC 64   // LL / CL
#define NBH 24  // B*H

typedef __bf16 bf16x8 __attribute__((ext_vector_type(8)));
typedef __bf16 bf16x4 __attribute__((ext_vector_type(4)));
typedef float floatx4 __attribute__((ext_vector_type(4)));

typedef const void __attribute__((address_space(1)))* gas_ptr;
typedef void __attribute__((address_space(3)))* las_ptr;

__device__ __forceinline__ void gl_lds16(const void* g, void* s) {
  __builtin_amdgcn_global_load_lds((gas_ptr)g, (las_ptr)s, 16, 0, 0);
}

__device__ __forceinline__ float wave_sum64(float v) {
#pragma unroll
  for (int off = 32; off; off >>= 1) v += __shfl_xor(v, off, 64);
  return v;
}

__device__ __forceinline__ float sigm(float x) { return 1.0f / (1.0f + expf(-x)); }
__device__ __forceinline__ float clamp5(float x) {
  return __builtin_amdgcn_fmed3f(x, -5.f, 5.f);
}

// ---------------- K1: prep — fused weight converts + conv+LN ----------------
// blocks [0,2048): conv_ln rows; blocks [2048, 4576): weight converts.
// convert group ranges (float4): wqb (qkv 442368 | bn1 49152) | proj 147456 | w2pad 8192
__global__ __launch_bounds__(256) void prep_kernel(
    const float* __restrict__ x, const float* __restrict__ cw,
    const float* __restrict__ cb, const float* __restrict__ g,
    const float* __restrict__ bta, __bf16* __restrict__ xn,
    const float* __restrict__ qkvw, const float* __restrict__ bnw1,
    const float* __restrict__ projw, const float* __restrict__ w2,
    __bf16* __restrict__ wqb, __bf16* __restrict__ dp, __bf16* __restrict__ dw2) {
  if (blockIdx.x >= 2048) {             // ---- convert path ----
    int i = (blockIdx.x - 2048) * 256 + threadIdx.x;
    if (i >= 647168) return;
    bf16x4 o;
    if (i >= 638976) {                  // w2 pad region (128x256 bf16)
      int off = i - 638976;
      if (off < 3840) {
        float4 v = ((const float4*)w2)[off];
        o[0] = (__bf16)v.x; o[1] = (__bf16)v.y; o[2] = (__bf16)v.z; o[3] = (__bf16)v.w;
      } else {
        o[0] = (__bf16)0.f; o[1] = (__bf16)0.f; o[2] = (__bf16)0.f; o[3] = (__bf16)0.f;
      }
      ((bf16x4*)dw2)[off] = o;
      return;
    }
    const float* s; __bf16* d; int off;
    if (i < 442368)      { s = qkvw;  d = wqb;  off = i; }
    else if (i < 491520) { s = bnw1;  d = wqb;  off = i; }      // contiguous concat
    else                 { s = projw; d = dp;   off = i - 491520; }
    int soff = (i < 442368) ? i : (i < 491520 ? i - 442368 : off);
    float4 v = ((const float4*)s)[soff];
    o[0] = (__bf16)v.x; o[1] = (__bf16)v.y; o[2] = (__bf16)v.z; o[3] = (__bf16)v.w;
    ((bf16x4*)d)[off] = o;
    return;
  }
  // ---- conv + LN path ----
  int row = blockIdx.x;            // b*L + l
  int l = row & (LL - 1);
  const float* xr = x + (size_t)row * DD;
  __shared__ float red[16];
  float vals[3];
  float s = 0.f, ss = 0.f;
#pragma unroll
  for (int i = 0; i < 3; i++) {
    int d = threadIdx.x + i * 256;
    float x0 = xr[d];
    float xm1 = (l >= 1) ? xr[d - DD] : 0.f;
    float xm2 = (l >= 2) ? xr[d - 2 * DD] : 0.f;
    float c = xm2 * cw[d * 3 + 0] + xm1 * cw[d * 3 + 1] + x0 * cw[d * 3 + 2] + cb[d];
    float v = x0 + c;
    vals[i] = v; s += v; ss += v * v;
  }
  s = wave_sum64(s); ss = wave_sum64(ss);
  int wid = threadIdx.x >> 6;
  if ((threadIdx.x & 63) == 0) { red[wid * 2] = s; red[wid * 2 + 1] = ss; }
  __syncthreads();
  if (threadIdx.x == 0) {
    red[8] = red[0] + red[2] + red[4] + red[6];
    red[9] = red[1] + red[3] + red[5] + red[7];
  }
  __syncthreads();
  float mu = red[8] * (1.f / 768.f);
  float var = red[9] * (1.f / 768.f) - mu * mu;
  float inv = rsqrtf(var + 1e-5f);
  __bf16* xo = xn + (size_t)row * DD;
#pragma unroll
  for (int i = 0; i < 3; i++) {
    int d = threadIdx.x + i * 256;
    xo[d] = (__bf16)((vals[i] - mu) * inv * g[d] + bta[d]);
  }
}

// ---------------- K2: bf16 MFMA GEMM  C = A(M,K) * B(N,K)^T + bias ----------
// BM x 128 tile, BK=64, global_load_lds staging, XOR-swizzled LDS chunks.
// MODE 0: plain fp32 out; MODE 3: fused qkv+bn epilogue
//   gcol<1536: +bias, elu+1 -> qkva fp32 (stride 2304)
//   1536..2303: +bias      -> qkva fp32
//   >=2304: silu           -> hbuf bf16 (stride 256)
template <int BM, int MODE, bool HASBIAS, bool OUTBF>
__global__ __launch_bounds__(256) void gemm_mfma_kernel(
    const __bf16* __restrict__ A, const __bf16* __restrict__ Bw,
    const float* __restrict__ bias, void* __restrict__ Cv, void* __restrict__ C2,
    int M, int N, int K) {
  constexpr int MI = BM / 32;
  __shared__ __attribute__((aligned(16))) __bf16 As[BM * 64];
  __shared__ __attribute__((aligned(16))) __bf16 Bs[128 * 64];
  int m0 = blockIdx.y * BM, n0 = blockIdx.x * 128;
  int tid = threadIdx.x;
  int w = tid >> 6, lane = tid & 63;
  int wm = w >> 1, wn = w & 1;
  int quad = lane >> 4, l16 = lane & 15;

  int lrow = lane >> 3;
  int lchunk = (lane & 7) ^ lrow;
  int R0 = w * 8;

  floatx4 acc[MI][4];
#pragma unroll
  for (int i = 0; i < MI; i++)
#pragma unroll
    for (int j = 0; j < 4; j++) acc[i][j] = (floatx4)0.f;

  for (int k0 = 0; k0 < K; k0 += 64) {
    __syncthreads();
#pragma unroll
    for (int r = 0; r < BM / 32; r++) {
      int row = r * 32 + R0 + lrow;
      gl_lds16(A + (size_t)(m0 + row) * K + k0 + lchunk * 8, &As[(r * 32 + R0) * 64]);
    }
#pragma unroll
    for (int r = 0; r < 4; r++) {
      int row = r * 32 + R0 + lrow;
      gl_lds16(Bw + (size_t)(n0 + row) * K + k0 + lchunk * 8, &Bs[(r * 32 + R0) * 64]);
    }
    __syncthreads();
#pragma unroll
    for (int s = 0; s < 2; s++) {
      bf16x8 af[MI], bfr[4];
      int csw = (s << 2) + quad;
#pragma unroll
      for (int i = 0; i < MI; i++) {
        int m = wm * (BM / 2) + i * 16 + l16;
        af[i] = *(const bf16x8*)&As[m * 64 + (csw ^ (l16 & 7)) * 8];
      }
#pragma unroll
      for (int j = 0; j < 4; j++) {
        int n = wn * 64 + j * 16 + l16;
        bfr[j] = *(const bf16x8*)&Bs[n * 64 + (csw ^ (l16 & 7)) * 8];
      }
#pragma unroll
      for (int i = 0; i < MI; i++)
#pragma unroll
        for (int j = 0; j < 4; j++)
          acc[i][j] = __builtin_amdgcn_mfma_f32_16x16x32_bf16(af[i], bfr[j], acc[i][j], 0, 0, 0);
    }
  }
#pragma unroll
  for (int j = 0; j < 4; j++) {
    int gcol = n0 + wn * 64 + j * 16 + l16;
    if (MODE == 3) {
      if (gcol < 2304) {
        float bv = bias[gcol];
        bool isqk = gcol < 1536;
#pragma unroll
        for (int i = 0; i < MI; i++) {
          int grow = m0 + wm * (BM / 2) + i * 16 + quad * 4;
#pragma unroll
          for (int r = 0; r < 4; r++) {
            float v = acc[i][j][r] + bv;
            if (isqk) v = (v > 0.f) ? v + 1.f : expf(v);
            ((float*)Cv)[(size_t)(grow + r) * 2304 + gcol] = v;
          }
        }
      } else {
        int hcol = gcol - 2304;
#pragma unroll
        for (int i = 0; i < MI; i++) {
          int grow = m0 + wm * (BM / 2) + i * 16 + quad * 4;
#pragma unroll
          for (int r = 0; r < 4; r++) {
            float v = acc[i][j][r];
            v = v / (1.f + expf(-v));
            ((__bf16*)C2)[(size_t)(grow + r) * 256 + hcol] = (__bf16)v;
          }
        }
      }
    } else {
      float bv = HASBIAS ? bias[gcol] : 0.f;
#pragma unroll
      for (int i = 0; i < MI; i++) {
        int grow = m0 + wm * (BM / 2) + i * 16 + quad * 4;
#pragma unroll
        for (int r = 0; r < 4; r++) {
          float v = acc[i][j][r] + bv;
          if (OUTBF) ((__bf16*)Cv)[(size_t)(grow + r) * N + gcol] = (__bf16)v;
          else       ((float*)Cv)[(size_t)(grow + r) * N + gcol] = v;
        }
      }
    }
  }
}

// ---------------- K3: params transform + df (fused, one block per bh) -------
__global__ __launch_bounds__(256) void params_df_kernel(
    const float* __restrict__ pp, const float* __restrict__ temp,
    float* __restrict__ gate, float* __restrict__ dec, float* __restrict__ dfb) {
  int bh = blockIdx.x;             // < 24
  int b = bh / HH, h = bh - b * HH;
  int tid = threadIdx.x;
  int lane = tid & 63, wid = tid >> 6;
  float tv = temp[0];
  const float PI = 3.14159265358979323846f;
  double ls[4];
  double lsum = 0.0;
#pragma unroll
  for (int i = 0; i < 4; i++) {
    int l = tid * 4 + i;
    int row = (b << 10) + l;
    const float* p = pp + (size_t)row * 128 + h * 5;
    float p0 = p[0], p1 = p[1], p2 = p[2], p3 = p[3], p4 = p[4];
    float sa = sigm(p0);
    float sp = tanhf(p1) * PI;
    float ca = sigm(p2);
    float cp = tanhf(p3) * PI;
    float dc = 0.3f + 0.65f * sigm(p4);
    float gt = sigm(sa * ca * cosf(sp - cp) * tv);
    gate[row * HH + h] = gt;
    dec[(bh << 10) + l] = dc;
    lsum += (double)logf(dc);
    ls[i] = lsum;
  }
  double run = lsum;
#pragma unroll
  for (int off = 1; off < 64; off <<= 1) {
    double n = __shfl_up(run, off, 64);
    if (lane >= off) run += n;
  }
  __shared__ double wsum[4];
  if (lane == 63) wsum[wid] = run;
  __syncthreads();
  double wexcl = 0.0;
  for (int k = 0; k < wid; k++) wexcl += wsum[k];
  double excl = wexcl + run - lsum;
  float* dfo = dfb + (bh << 10) + tid * 4;
#pragma unroll
  for (int i = 0; i < 4; i++) dfo[i] = expf((float)(excl + ls[i]));
}

// ---------------- K5: scan phase1 — d-split, 4 waves/block, bf16 kvcs -------
__global__ __launch_bounds__(256) void scan_phase1(
    const float* __restrict__ qkv, const float* __restrict__ dec,
    const float* __restrict__ df, const float* __restrict__ gate,
    __bf16* __restrict__ kvcs, float* __restrict__ zcs, float* __restrict__ Aarr) {
  int blk = blockIdx.x;            // bh*NC + c
  int bh = blk >> 6, c = blk & (NC - 1);
  int b = bh / HH, h = bh - b * HH;
  int tid = threadIdx.x;
  int w = tid >> 6, e = tid & 63;
  int t0 = c * CL;
  __shared__ __attribute__((aligned(16))) float kbuf[CL][64];
  __shared__ __attribute__((aligned(16))) float vbuf[CL][64];
  __shared__ float sbuf[CL][4];
  const float* base = qkv + ((size_t)(b * LL + t0)) * 2304 + h * 64;
  {
    int t = (w << 2) + (e >> 4);
    int col = (e & 15) << 2;
    gl_lds16(base + (size_t)t * 2304 + 768 + col, &kbuf[w << 2][0]);
    gl_lds16(base + (size_t)t * 2304 + 1536 + col, &vbuf[w << 2][0]);
  }
  if (tid < CL) {
    int t = t0 + tid;
    float a = dec[bh * LL + t];
    float d = df[bh * LL + t];
    float r = d / (d + 1e-8f);
    float g = gate[(b * LL + t) * HH + h];
    sbuf[tid][0] = a; sbuf[tid][1] = r; sbuf[tid][2] = g * (1.f - a);
    sbuf[tid][3] = (1.f - a) * r;
  }
  __syncthreads();
  float KV[16];
#pragma unroll
  for (int d = 0; d < 16; d++) KV[d] = 0.f;
  float z = 0.f, A = 1.f;
  for (int t = 0; t < CL; t++) {
    float a = sbuf[t][0], r = sbuf[t][1], cs = sbuf[t][2], w1r = sbuf[t][3];
    float vc = vbuf[t][e] * cs;
    A *= a;
#pragma unroll
    for (int d4 = 0; d4 < 4; d4++) {
      float4 k4 = *(const float4*)&kbuf[t][(w << 4) + (d4 << 2)];
      float kr[4] = {k4.x, k4.y, k4.z, k4.w};
#pragma unroll
      for (int j = 0; j < 4; j++) {
        float u = clamp5(kr[j] * vc);
        KV[(d4 << 2) + j] = fmaf(a, KV[(d4 << 2) + j], r * u);
      }
    }
    z = fmaf(a, z, kbuf[t][e] * w1r);
  }
  __bf16* kvo = kvcs + (size_t)blk * 4096 + (w << 4) * 64 + e;
#pragma unroll
  for (int d = 0; d < 16; d++) kvo[d * 64] = (__bf16)KV[d];
  if (w == 0) zcs[blk * 64 + e] = z;
  if (tid == 0) Aarr[blk] = A;
}

// ---------------- K6: sequential carry combine (in-place end->init) ---------
__global__ __launch_bounds__(256) void combine_kernel(
    const float* __restrict__ Aarr, __bf16* __restrict__ kv, float* __restrict__ z) {
  int g = blockIdx.x * 256 + threadIdx.x;
  if (g < NBH * 4096) {
    int bh = g >> 12, idx = g & 4095;
    const float* Ap = Aarr + bh * NC;
    __bf16* p = kv + (size_t)bh * NC * 4096 + idx;
    float carry = 0.f;
#pragma unroll 8
    for (int c = 0; c < NC; c++) {
      float endv = (float)p[(size_t)c * 4096];
      p[(size_t)c * 4096] = (__bf16)carry;
      carry = fmaf(Ap[c], carry, endv);
    }
  } else {
    int g2 = g - NBH * 4096;
    if (g2 >= NBH * 64) return;
    int bh = g2 >> 6, idx = g2 & 63;
    const float* Ap = Aarr + bh * NC;
    float* p = z + bh * NC * 64 + idx;
    float carry = 0.f;
#pragma unroll 8
    for (int c = 0; c < NC; c++) {
      float endv = p[c * 64];
      p[c * 64] = carry;
      carry = fmaf(Ap[c], carry, endv);
    }
  }
}

// ---------------- K7: scan phase3 — barrier-free t-loop, batched epilogue ---
__global__ __launch_bounds__(256) void scan_phase3(
    const float* __restrict__ qkv, const float* __restrict__ dec,
    const float* __restrict__ df, const float* __restrict__ gate,
    const __bf16* __restrict__ kvcs, const float* __restrict__ zcs,
    const float* __restrict__ mng, const float* __restrict__ mnb,
    __bf16* __restrict__ att) {
  int blk = blockIdx.x;
  int bh = blk >> 6, c = blk & (NC - 1);
  int b = bh / HH, h = bh - b * HH;
  int tid = threadIdx.x;
  int w = tid >> 6, e = tid & 63;
  int t0 = c * CL;
  __shared__ __attribute__((aligned(16))) float qbuf[CL][64];
  __shared__ __attribute__((aligned(16))) float kbuf[CL][64];
  __shared__ __attribute__((aligned(16))) float vbuf[CL][64];
  __shared__ float sbuf[CL][4];
  __shared__ float pbuf[CL][4][64];
  const float* base = qkv + ((size_t)(b * LL + t0)) * 2304 + h * 64;
  {
    int t = (w << 2) + (e >> 4);
    int col = (e & 15) << 2;
    gl_lds16(base + (size_t)t * 2304 + col, &qbuf[w << 2][0]);
    gl_lds16(base + (size_t)t * 2304 + 768 + col, &kbuf[w << 2][0]);
    gl_lds16(base + (size_t)t * 2304 + 1536 + col, &vbuf[w << 2][0]);
  }
  if (tid < CL) {
    int t = t0 + tid;
    float a = dec[bh * LL + t];
    float d = df[bh * LL + t];
    float r = d / (d + 1e-8f);
    float g = gate[(b * LL + t) * HH + h];
    sbuf[tid][0] = a; sbuf[tid][1] = r; sbuf[tid][2] = g * (1.f - a);
    sbuf[tid][3] = (1.f - a) * r;
  }
  float KV[16];
  const __bf16* kvi = kvcs + (size_t)blk * 4096 + (w << 4) * 64 + e;
#pragma unroll
  for (int d = 0; d < 16; d++) KV[d] = (float)kvi[d * 64];
  float z = zcs[blk * 64 + e];
  float zsnap[4];
  __syncthreads();
  for (int t = 0; t < CL; t++) {
    float a = sbuf[t][0], r = sbuf[t][1], cs = sbuf[t][2], w1r = sbuf[t][3];
    float vc = vbuf[t][e] * cs;
    float onp = 0.f;
#pragma unroll
    for (int d4 = 0; d4 < 4; d4++) {
      float4 k4 = *(const float4*)&kbuf[t][(w << 4) + (d4 << 2)];
      float4 q4 = *(const float4*)&qbuf[t][(w << 4) + (d4 << 2)];
      float kr[4] = {k4.x, k4.y, k4.z, k4.w};
      float qr[4] = {q4.x, q4.y, q4.z, q4.w};
#pragma unroll
      for (int j = 0; j < 4; j++) {
        float u = clamp5(kr[j] * vc);
        float nv = fmaf(a, KV[(d4 << 2) + j], r * u);
        KV[(d4 << 2) + j] = nv;
        onp = fmaf(qr[j], nv, onp);
      }
    }
    pbuf[t][w][e] = onp;
    z = fmaf(a, z, kbuf[t][e] * w1r);
    if ((t >> 2) == w) zsnap[t & 3] = z;
  }
  __syncthreads();
  float mg = mng[e], mb = mnb[e];
#pragma unroll
  for (int i = 0; i < 4; i++) {
    int t = (w << 2) + i;
    float on = pbuf[t][0][e] + pbuf[t][1][e] + pbuf[t][2][e] + pbuf[t][3][e];
    float zc = __builtin_amdgcn_fmed3f(zsnap[i], -10000.f, 10000.f);
    float qe = qbuf[t][e];
    float s0 = qe * zc, s1 = on, s2 = on * on;
#pragma unroll
    for (int off = 32; off; off >>= 1) {
      s0 += __shfl_xor(s0, off, 64);
      s1 += __shfl_xor(s1, off, 64);
      s2 += __shfl_xor(s2, off, 64);
    }
    float den = s0 + 1e-4f;
    float idn = 1.f / den;
    float o = on * idn;
    float mu = s1 * idn * (1.f / 64.f);
    float E2 = s2 * idn * idn * (1.f / 64.f);
    float var = E2 - mu * mu;
    float outv = (o - mu) * rsqrtf(var + 1e-5f) * mg + mb;
    att[((size_t)(b * LL + t0 + t)) * DD + h * 64 + e] = (__bf16)outv;
  }
}

// ---------------------------------------------------------------------------
extern "C" void kernel_launch(void* const* d_in, const int* in_sizes, int n_in,
                              void* d_out, int out_size, void* d_ws, size_t ws_size,
                              hipStream_t stream) {
  (void)in_sizes; (void)n_in; (void)out_size; (void)ws_size;
  const float* x           = (const float*)d_in[0];
  const float* conv_w      = (const float*)d_in[1];
  const float* conv_b      = (const float*)d_in[2];
  const float* ln_g        = (const float*)d_in[3];
  const float* ln_b        = (const float*)d_in[4];
  const float* qkv_w       = (const float*)d_in[5];
  const float* qkv_b       = (const float*)d_in[6];
  const float* bn_w1       = (const float*)d_in[7];
  const float* bn_w2       = (const float*)d_in[8];
  const float* temperature = (const float*)d_in[9];
  const float* proj_w      = (const float*)d_in[10];
  const float* proj_b      = (const float*)d_in[11];
  const float* mn_g        = (const float*)d_in[12];
  const float* mn_b        = (const float*)d_in[13];

  float* y    = (float*)d_out;
  float* gate = y + 2 * 1024 * 768;      // outputs concatenated: y then gate

  char* ws = (char*)d_ws;
  __bf16* xn_bf   = (__bf16*)(ws);                // 3.15 MB, reused as att_bf
  __bf16* att_bf  = xn_bf;                        // alias (xn dead before phase3)
  float*  qkva    = (float*)(ws + 3145728);       // 18.87 MB
  __bf16* hbuf_bf = (__bf16*)(ws + 22020096);     // 1.05 MB (2048x256 bf16)
  float*  pp      = (float*)(ws + 23068672);      // 1.05 MB (2048x128 fp32)
  float*  dec     = (float*)(ws + 24117248);      // 96 KB  (B,H,L)
  float*  dfb     = (float*)(ws + 24215552);      // 96 KB
  __bf16* kvcs    = (__bf16*)(ws + 24313856);     // 12.58 MB bf16 (end->init in place)
  __bf16* wqb_bf  = (__bf16*)(ws + 24313856);     // 3.93 MB alias (dead before phase1)
  float*  zcs     = (float*)(ws + 36896768);      // 384 KB
  float*  Aarr    = (float*)(ws + 37289984);      // 6 KB
  __bf16* projw_bf= (__bf16*)(ws + 37296128);     // 1.18 MB
  __bf16* w2p_bf  = (__bf16*)(ws + 38475776);     // 64 KB -> total 38.5 MB

  // prep: conv+LN (blocks 0..2047) + all weight converts (blocks 2048..4575)
  prep_kernel<<<4576, 256, 0, stream>>>(x, conv_w, conv_b, ln_g, ln_b, xn_bf,
                                        qkv_w, bn_w1, proj_w, bn_w2,
                                        wqb_bf, projw_bf, w2p_bf);

  // fused qkv+bn1: [q|k|v -> qkva fp32 (elu+1 on q,k)] + [silu -> hbuf bf16]
  gemm_mfma_kernel<64, 3, true, false><<<dim3(20, 32), 256, 0, stream>>>(
      xn_bf, wqb_bf, qkv_b, qkva, hbuf_bf, 2048, 2560, 768);

  // pp = h @ w2p.T  (N=128, rows>=60 zero-padded)
  gemm_mfma_kernel<64, 0, false, false><<<dim3(1, 32), 256, 0, stream>>>(
      hbuf_bf, w2p_bf, nullptr, pp, nullptr, 2048, 128, 256);

  params_df_kernel<<<NBH, 256, 0, stream>>>(pp, temperature, gate, dec, dfb);

  scan_phase1<<<NBH * NC, 256, 0, stream>>>(qkva, dec, dfb, gate, kvcs, zcs, Aarr);

  combine_kernel<<<390, 256, 0, stream>>>(Aarr, kvcs, zcs);

  scan_phase3<<<NBH * NC, 256, 0, stream>>>(qkva, dec, dfb, gate, kvcs, zcs,
                                            mn_g, mn_b, att_bf);

  // y = att @ proj_w.T + proj_b
  gemm_mfma_kernel<64, 0, true, false><<<dim3(6, 32), 256, 0, stream>>>(
      att_bf, projw_bf, proj_b, y, nullptr, 2048, 768, 768);
}